// Round 11
// baseline (379.391 us; speedup 1.0000x reference)
//
#include <hip/hip_runtime.h>
#include <math.h>

#define N_NODES 50000
#define N_EDGESC 2000
#define N_INC   200000
#define SEQ     64
#define FEATN   6
#define CH      32
#define OUTF    5
#define SLOPE   0.01f

typedef __attribute__((ext_vector_type(8))) short bf16x8;
typedef __attribute__((ext_vector_type(4))) float f32x4;

__device__ __forceinline__ float fast_rcp(float x) { return __builtin_amdgcn_rcpf(x); }
__device__ __forceinline__ float sigm(float x) { return fast_rcp(1.f + __expf(-x)); }
__device__ __forceinline__ float tanh_fast(float x) { return 1.f - 2.f * fast_rcp(1.f + __expf(2.f * x)); }
__device__ __forceinline__ float leaky(float v) { return v > 0.f ? v : SLOPE * v; }

__device__ __forceinline__ ushort f2bf(float x) {
  uint u = __float_as_uint(x);
  u = u + 0x7fffu + ((u >> 16) & 1u);
  return (ushort)(u >> 16);
}
__device__ __forceinline__ float bf2f(ushort s) {
  return __uint_as_float(((uint)s) << 16);
}
__device__ __forceinline__ uint pk_bf16(float a, float b) {
  uint r;
  asm("v_cvt_pk_bf16_f32 %0, %1, %2" : "=v"(r) : "v"(a), "v"(b));
  return r;
}

union BW { bf16x8 v; uint w[4]; uint2 d[2]; };

// ---------------- GRU via MFMA: one 64-thread block = one wave = 16 nodes ----------------
// Round-11: BUILTIN mfma restored (rounds 8-10 showed inline-asm MFMA is
// schedule-fragile: LLVM's hazard recognizer doesn't see INLINE_ASM as MAI,
// so D-write -> VALU-read wait states are omitted; r8 passed by scheduling
// luck, r9/r10 failed).  Math byte-identical to rounds 6/7 (6.1e-5 known
// good).  Only change vs round 7: 1-wave blocks, grid 3125 (load balance).
__global__ __launch_bounds__(64) void gru_mfma_kernel(
    const float* __restrict__ price,
    const float* __restrict__ w_ih, const float* __restrict__ w_hh,
    const float* __restrict__ b_ih, const float* __restrict__ b_hh,
    float* __restrict__ Y)
{
  __shared__ __align__(16) ushort Hh[16 * 40];
  __shared__ __align__(16) ushort Hl[16 * 40];

  const int lane = threadIdx.x & 63;
  const int q    = lane >> 4;   // k-group / D-row-quad
  const int m    = lane & 15;   // node-in-wave
  const int node = blockIdx.x * 16 + m;   // grid 3125*16 = 50000 exactly

  // ---- Whh A-frags (hi/lo split) ----
  bf16x8 WAhi[6], WAlo[6];
#pragma unroll
  for (int tt = 0; tt < 6; ++tt) {
    const float* wr = w_hh + (tt * 16 + m) * CH + 8 * q;
    float4 v0 = *(const float4*)(wr);
    float4 v1 = *(const float4*)(wr + 4);
    float vv[8] = {v0.x, v0.y, v0.z, v0.w, v1.x, v1.y, v1.z, v1.w};
#pragma unroll
    for (int e = 0; e < 8; ++e) {
      ushort h = f2bf(vv[e]);
      WAhi[tt][e] = (short)h;
      WAlo[tt][e] = (short)f2bf(vv[e] - bf2f(h));
    }
  }

  // ---- GI A-frags: K packing per gate-row g = 16*tt + m ----
  bf16x8 GA[6];
#pragma unroll
  for (int tt = 0; tt < 6; ++tt) {
    int g = tt * 16 + m;
    bf16x8 a = {0, 0, 0, 0, 0, 0, 0, 0};
    if (q < 3) {
      float w[6];
#pragma unroll
      for (int f = 0; f < FEATN; ++f) w[f] = w_ih[g * FEATN + f];
      ushort wh[6]; float wl[6];
#pragma unroll
      for (int f = 0; f < FEATN; ++f) { wh[f] = f2bf(w[f]); wl[f] = w[f] - bf2f(wh[f]); }
      if (q == 0) {
#pragma unroll
        for (int f = 0; f < 6; ++f) a[f] = (short)wh[f];
        a[6] = (short)wh[0]; a[7] = (short)wh[1];
      } else if (q == 1) {
#pragma unroll
        for (int f = 0; f < 4; ++f) a[f] = (short)wh[2 + f];
#pragma unroll
        for (int f = 0; f < 4; ++f) a[4 + f] = (short)f2bf(wl[f]);
      } else {
        a[0] = (short)f2bf(wl[4]);
        a[1] = (short)f2bf(wl[5]);
        float bias = b_ih[g] + (g < 64 ? b_hh[g] : 0.f);
        ushort bh = f2bf(bias);
        a[2] = (short)bh;
        a[3] = (short)f2bf(bias - bf2f(bh));
      }
    }
    GA[tt] = a;
  }

  float bhn[8];
#pragma unroll
  for (int i = 0; i < 4; ++i) {
    bhn[i]     = b_hh[64 + 4 * q + i];
    bhn[4 + i] = b_hh[80 + 4 * q + i];
  }

  {
    uint2 z; z.x = 0; z.y = 0;
    *(uint2*)(Hh + m * 40 + 4 * q) = z;
    *(uint2*)(Hh + m * 40 + 16 + 4 * q) = z;
    *(uint2*)(Hl + m * 40 + 4 * q) = z;
    *(uint2*)(Hl + m * 40 + 16 + 4 * q) = z;
  }

  float h_f32[8];
#pragma unroll
  for (int i = 0; i < 8; ++i) h_f32[i] = 0.f;

  const float* xp = price + node * (SEQ * FEATN);
  float xc[6], xn[6];
  if (q < 3) {
    float2 a0 = *(const float2*)(xp);
    float2 a1 = *(const float2*)(xp + 2);
    float2 a2 = *(const float2*)(xp + 4);
    xc[0] = a0.x; xc[1] = a0.y; xc[2] = a1.x; xc[3] = a1.y; xc[4] = a2.x; xc[5] = a2.y;
  }

  const f32x4 zz = {0.f, 0.f, 0.f, 0.f};

  for (int t = 0; t < SEQ; ++t) {
    // ---- build x B-frag via packed cvt (hi/lo split), guarded as in r6/r7 ----
    BW bx; bx.w[0] = 0; bx.w[1] = 0; bx.w[2] = 0; bx.w[3] = 0;
    if (q < 3) {
      uint p01 = pk_bf16(xc[0], xc[1]);
      uint p23 = pk_bf16(xc[2], xc[3]);
      uint p45 = pk_bf16(xc[4], xc[5]);
      float l0 = xc[0] - __uint_as_float(p01 << 16);
      float l1 = xc[1] - __uint_as_float(p01 & 0xFFFF0000u);
      float l2 = xc[2] - __uint_as_float(p23 << 16);
      float l3 = xc[3] - __uint_as_float(p23 & 0xFFFF0000u);
      float l4 = xc[4] - __uint_as_float(p45 << 16);
      float l5 = xc[5] - __uint_as_float(p45 & 0xFFFF0000u);
      if (q == 0) {
        bx.w[0] = p01; bx.w[1] = p23; bx.w[2] = p45;
        bx.w[3] = pk_bf16(l0, l1);
      } else if (q == 1) {
        bx.w[0] = pk_bf16(l2, l3); bx.w[1] = pk_bf16(l4, l5);
        bx.w[2] = p01; bx.w[3] = p23;
      } else {
        bx.w[0] = p45; bx.w[1] = 0x3F803F80u;
      }
    }
    bf16x8 Bx = bx.v;

    // prefetch next step's x
    if (t + 1 < SEQ && q < 3) {
      const float* nx = xp + (t + 1) * FEATN;
      float2 a0 = *(const float2*)(nx);
      float2 a1 = *(const float2*)(nx + 2);
      float2 a2 = *(const float2*)(nx + 4);
      xn[0] = a0.x; xn[1] = a0.y; xn[2] = a1.x; xn[3] = a1.y; xn[4] = a2.x; xn[5] = a2.y;
    }

    // ---- H B-frags from LDS ----
    bf16x8 HhF = *(bf16x8*)(Hh + m * 40 + 8 * q);
    bf16x8 HlF = *(bf16x8*)(Hl + m * 40 + 8 * q);

    // ---- MFMAs (builtins: hazard-safe lowering) ----
    f32x4 aRZ[4], aNh[2], aNi[2];
#pragma unroll
    for (int tt = 0; tt < 4; ++tt) {
      f32x4 a = __builtin_amdgcn_mfma_f32_16x16x32_bf16(GA[tt], Bx, zz, 0, 0, 0);
      a = __builtin_amdgcn_mfma_f32_16x16x32_bf16(WAlo[tt], HhF, a, 0, 0, 0);
      a = __builtin_amdgcn_mfma_f32_16x16x32_bf16(WAhi[tt], HlF, a, 0, 0, 0);
      a = __builtin_amdgcn_mfma_f32_16x16x32_bf16(WAhi[tt], HhF, a, 0, 0, 0);
      aRZ[tt] = a;
    }
#pragma unroll
    for (int tt = 0; tt < 2; ++tt) {
      f32x4 a = __builtin_amdgcn_mfma_f32_16x16x32_bf16(WAlo[4 + tt], HhF, zz, 0, 0, 0);
      a = __builtin_amdgcn_mfma_f32_16x16x32_bf16(WAhi[4 + tt], HlF, a, 0, 0, 0);
      a = __builtin_amdgcn_mfma_f32_16x16x32_bf16(WAhi[4 + tt], HhF, a, 0, 0, 0);
      aNh[tt] = a;
      aNi[tt] = __builtin_amdgcn_mfma_f32_16x16x32_bf16(GA[4 + tt], Bx, zz, 0, 0, 0);
    }

    // ---- gates + h-update (lane-local) ----
    float hv[8];
#pragma unroll
    for (int s = 0; s < 2; ++s) {
#pragma unroll
      for (int i = 0; i < 4; ++i) {
        int u = s * 4 + i;
        float r  = sigm(aRZ[s][i]);
        float z  = sigm(aRZ[2 + s][i]);
        float n  = tanh_fast(aNi[s][i] + r * (aNh[s][i] + bhn[u]));
        float h2 = n + z * (h_f32[u] - n);
        h_f32[u] = h2;
        hv[u] = h2;
      }
    }

    // ---- packed H writeback (hi + lo), dword stores ----
    uint ph0 = pk_bf16(hv[0], hv[1]);
    uint ph1 = pk_bf16(hv[2], hv[3]);
    uint ph2 = pk_bf16(hv[4], hv[5]);
    uint ph3 = pk_bf16(hv[6], hv[7]);
    float e0 = hv[0] - __uint_as_float(ph0 << 16);
    float e1 = hv[1] - __uint_as_float(ph0 & 0xFFFF0000u);
    float e2 = hv[2] - __uint_as_float(ph1 << 16);
    float e3 = hv[3] - __uint_as_float(ph1 & 0xFFFF0000u);
    float e4 = hv[4] - __uint_as_float(ph2 << 16);
    float e5 = hv[5] - __uint_as_float(ph2 & 0xFFFF0000u);
    float e6 = hv[6] - __uint_as_float(ph3 << 16);
    float e7 = hv[7] - __uint_as_float(ph3 & 0xFFFF0000u);
    uint2 wa, wb;
    wa.x = ph0; wa.y = ph1; wb.x = ph2; wb.y = ph3;
    *(uint2*)(Hh + m * 40 + 4 * q) = wa;
    *(uint2*)(Hh + m * 40 + 16 + 4 * q) = wb;
    wa.x = pk_bf16(e0, e1); wa.y = pk_bf16(e2, e3);
    wb.x = pk_bf16(e4, e5); wb.y = pk_bf16(e6, e7);
    *(uint2*)(Hl + m * 40 + 4 * q) = wa;
    *(uint2*)(Hl + m * 40 + 16 + 4 * q) = wb;

    if (q < 3) {
#pragma unroll
      for (int f = 0; f < 6; ++f) xc[f] = xn[f];
    }
  }

  // ---- epilogue: coalesced Y write, h = hi + lo from LDS ----
  {
    int mm = lane >> 2, c = lane & 3;
    int onode = blockIdx.x * 16 + mm;
    bf16x8 vh = *(bf16x8*)(Hh + mm * 40 + c * 8);
    bf16x8 vl = *(bf16x8*)(Hl + mm * 40 + c * 8);
    float o[8];
#pragma unroll
    for (int e = 0; e < 8; ++e) o[e] = bf2f((ushort)vh[e]) + bf2f((ushort)vl[e]);
    float4 o0; o0.x = o[0]; o0.y = o[1]; o0.z = o[2]; o0.w = o[3];
    float4 o1; o1.x = o[4]; o1.y = o[5]; o1.z = o[6]; o1.w = o[7];
    *(float4*)(Y + onode * CH + c * 8) = o0;
    *(float4*)(Y + onode * CH + c * 8 + 4) = o1;
  }
}

// ---------------- degree counting ----------------
__global__ __launch_bounds__(256) void deg_kernel(
    const int* __restrict__ nodes, const int* __restrict__ edges,
    int* __restrict__ DN, int* __restrict__ DE)
{
  int i = blockIdx.x * 256 + threadIdx.x;
  if (i < N_INC) {
    atomicAdd(&DN[nodes[i]], 1);
    atomicAdd(&DE[edges[i]], 1);
  }
}

// ---------------- exclusive scan of edge degrees (single block, 2000) ----------------
__global__ __launch_bounds__(256) void scan_kernel(const int* __restrict__ DE, int* __restrict__ OFF)
{
  __shared__ int part[256];
  int t = threadIdx.x;
  int c[8]; int sum = 0;
#pragma unroll
  for (int u = 0; u < 8; ++u) {
    int idx = t * 8 + u;
    int x = (idx < N_EDGESC) ? DE[idx] : 0;
    c[u] = x; sum += x;
  }
  part[t] = sum;
  __syncthreads();
  for (int d = 1; d < 256; d <<= 1) {
    int v = (t >= d) ? part[t - d] : 0;
    __syncthreads();
    part[t] += v;
    __syncthreads();
  }
  int base = part[t] - sum;
#pragma unroll
  for (int u = 0; u < 8; ++u) {
    int idx = t * 8 + u;
    if (idx <= N_EDGESC) OFF[idx] = base;
    base += c[u];
  }
}

// ---------------- exclusive scan of node degrees (single block 1024, 50000) ----------------
#define NPER 49  // 1024*49 >= 50000
__global__ __launch_bounds__(1024) void nscan_kernel(
    const int* __restrict__ DN, int* __restrict__ NOFF, int* __restrict__ CUR)
{
  __shared__ int part[1024];
  int t = threadIdx.x;
  int cl[NPER]; int sum = 0;
  int base_i = t * NPER;
#pragma unroll
  for (int u = 0; u < NPER; ++u) {
    int idx = base_i + u;
    int x = (idx < N_NODES) ? DN[idx] : 0;
    cl[u] = x; sum += x;
  }
  part[t] = sum;
  __syncthreads();
  for (int d = 1; d < 1024; d <<= 1) {
    int v = (t >= d) ? part[t - d] : 0;
    __syncthreads();
    part[t] += v;
    __syncthreads();
  }
  int run = part[t] - sum;  // exclusive
#pragma unroll
  for (int u = 0; u < NPER; ++u) {
    int idx = base_i + u;
    if (idx < N_NODES) { NOFF[idx] = run; CUR[idx] = run; }
    run += cl[u];
  }
  if (t == 1023) NOFF[N_NODES] = run;
}

// ---------------- bucket incidences by node: INCN[pos] = edge ----------------
__global__ __launch_bounds__(256) void bucket_kernel(
    const int* __restrict__ nodes, const int* __restrict__ edges,
    int* __restrict__ CUR, int* __restrict__ INCN)
{
  int i = blockIdx.x * 256 + threadIdx.x;
  if (i < N_INC) {
    int p = atomicAdd(&CUR[nodes[i]], 1);
    INCN[p] = edges[i];
  }
}

// ---------------- node->edge gather-sum + fused theta (256 thr, 2-way ILP) ----------------
__global__ __launch_bounds__(256) void edge_gather_kernel(
    const float* __restrict__ X, const int* __restrict__ nodes,
    const int* __restrict__ OFF, const float* __restrict__ theta,
    float* __restrict__ EF)
{
  int e = blockIdx.x;
  int s = OFF[e], tE = OFF[e + 1];
  int f = threadIdx.x & 31, g = threadIdx.x >> 5;  // 8 row-groups
  float a0 = 0.f, a1 = 0.f;
  for (int i = s + g; i < tE; i += 16) {
    a0 += X[nodes[i] * CH + f];
    if (i + 8 < tE) a1 += X[nodes[i + 8] * CH + f];
  }
  __shared__ float red[8][33];
  __shared__ __align__(16) float e32[32];
  red[g][f] = a0 + a1;
  __syncthreads();
  if (threadIdx.x < 32) {
    float acc = 0.f;
#pragma unroll
    for (int r = 0; r < 8; ++r) acc += red[r][f];
    int cnt = tE - s;
    float binv = cnt > 0 ? 1.f / (float)cnt : 0.f;
    e32[f] = acc * binv;
    float s0 = 0.f, s1 = 0.f;
#pragma unroll
    for (int k4 = 0; k4 < 8; ++k4) {
      float4 ev = *(float4*)(e32 + 4 * k4);
      float4 tv = *(const float4*)(theta + f * CH + 4 * k4);
      s0 += tv.x * ev.x + tv.z * ev.z;
      s1 += tv.y * ev.y + tv.w * ev.w;
    }
    EF[e * CH + f] = s0 + s1;
  }
}

// ---------------- edge->node CSR gather + finalize (conv1) ----------------
__global__ __launch_bounds__(256) void node_gather_kernel(
    const float* __restrict__ EF, const int* __restrict__ NOFF,
    const int* __restrict__ INCN, const float* __restrict__ bias,
    float* __restrict__ X)
{
  int gid = blockIdx.x * 256 + threadIdx.x;
  if (gid >= N_NODES * 8) return;
  int n = gid >> 3, q = gid & 7;
  int s = NOFF[n], e = NOFF[n + 1];
  float4 acc = make_float4(0.f, 0.f, 0.f, 0.f);
  float4 acc2 = make_float4(0.f, 0.f, 0.f, 0.f);
  int k = s;
  for (; k + 1 < e; k += 2) {
    int e0 = INCN[k], e1 = INCN[k + 1];
    float4 v0 = *(const float4*)(EF + e0 * CH + q * 4);
    float4 v1 = *(const float4*)(EF + e1 * CH + q * 4);
    acc.x += v0.x; acc.y += v0.y; acc.z += v0.z; acc.w += v0.w;
    acc2.x += v1.x; acc2.y += v1.y; acc2.z += v1.z; acc2.w += v1.w;
  }
  if (k < e) {
    float4 v0 = *(const float4*)(EF + INCN[k] * CH + q * 4);
    acc.x += v0.x; acc.y += v0.y; acc.z += v0.z; acc.w += v0.w;
  }
  int d = e - s;
  float dinv = d > 0 ? 1.f / (float)d : 0.f;
  float4 b = *(const float4*)(bias + 4 * q);
  float4 o;
  o.x = leaky(fmaf(acc.x + acc2.x, dinv, b.x));
  o.y = leaky(fmaf(acc.y + acc2.y, dinv, b.y));
  o.z = leaky(fmaf(acc.z + acc2.z, dinv, b.z));
  o.w = leaky(fmaf(acc.w + acc2.w, dinv, b.w));
  *(float4*)(X + n * CH + 4 * q) = o;
}

// ---------------- edge->node CSR gather + finalize + output linear (conv2) ----------------
__global__ __launch_bounds__(256) void node_gather_out_kernel(
    const float* __restrict__ EF, const int* __restrict__ NOFF,
    const int* __restrict__ INCN, const float* __restrict__ bias,
    const float* __restrict__ w_out, const float* __restrict__ b_out,
    float* __restrict__ out)
{
  int gid = blockIdx.x * 256 + threadIdx.x;
  if (gid >= N_NODES * 8) return;
  int n = gid >> 3, q = gid & 7;
  int s = NOFF[n], e = NOFF[n + 1];
  float4 acc = make_float4(0.f, 0.f, 0.f, 0.f);
  float4 acc2 = make_float4(0.f, 0.f, 0.f, 0.f);
  int k = s;
  for (; k + 1 < e; k += 2) {
    int e0 = INCN[k], e1 = INCN[k + 1];
    float4 v0 = *(const float4*)(EF + e0 * CH + q * 4);
    float4 v1 = *(const float4*)(EF + e1 * CH + q * 4);
    acc.x += v0.x; acc.y += v0.y; acc.z += v0.z; acc.w += v0.w;
    acc2.x += v1.x; acc2.y += v1.y; acc2.z += v1.z; acc2.w += v1.w;
  }
  if (k < e) {
    float4 v0 = *(const float4*)(EF + INCN[k] * CH + q * 4);
    acc.x += v0.x; acc.y += v0.y; acc.z += v0.z; acc.w += v0.w;
  }
  int d = e - s;
  float dinv = d > 0 ? 1.f / (float)d : 0.f;
  float4 b = *(const float4*)(bias + 4 * q);
  float v0 = leaky(fmaf(acc.x + acc2.x, dinv, b.x));
  float v1 = leaky(fmaf(acc.y + acc2.y, dinv, b.y));
  float v2 = leaky(fmaf(acc.z + acc2.z, dinv, b.z));
  float v3 = leaky(fmaf(acc.w + acc2.w, dinv, b.w));

  float p[OUTF];
#pragma unroll
  for (int o = 0; o < OUTF; ++o) {
    const float* wr = w_out + o * CH + 4 * q;
    p[o] = v0 * wr[0] + v1 * wr[1] + v2 * wr[2] + v3 * wr[3];
  }
#pragma unroll
  for (int off = 1; off < 8; off <<= 1) {
#pragma unroll
    for (int o = 0; o < OUTF; ++o) p[o] += __shfl_xor(p[o], off);
  }
  if (q < OUTF) out[n * OUTF + q] = leaky(p[q] + b_out[q]);
}

extern "C" void kernel_launch(void* const* d_in, const int* in_sizes, int n_in,
                              void* d_out, int out_size, void* d_ws, size_t ws_size,
                              hipStream_t stream)
{
  const float* price   = (const float*)d_in[0];
  const int*   e_nodes = (const int*)d_in[1];
  const int*   e_edges = (const int*)d_in[2];
  const float* w_ih    = (const float*)d_in[6];
  const float* w_hh    = (const float*)d_in[7];
  const float* b_ih    = (const float*)d_in[8];
  const float* b_hh    = (const float*)d_in[9];
  const float* theta1  = (const float*)d_in[10];
  const float* bias1   = (const float*)d_in[11];
  const float* theta2  = (const float*)d_in[12];
  const float* bias2   = (const float*)d_in[13];
  const float* w_out   = (const float*)d_in[14];
  const float* b_out   = (const float*)d_in[15];
  float* out = (float*)d_out;

  float* ws   = (float*)d_ws;
  float* Y    = ws;                    // [50000*32]
  float* EF   = ws + 1600000;          // [2000*32]
  int*   DN   = (int*)(ws + 1664000);  // [50000]
  int*   DE   = DN + N_NODES;          // [2000]
  int*   OFF  = DE + N_EDGESC;         // [2001]
  int*   NOFF = OFF + N_EDGESC + 1;    // [50001]
  int*   CUR  = NOFF + N_NODES + 1;    // [50000]
  int*   INCN = CUR + N_NODES;         // [200000]

  hipMemsetAsync(DN, 0, (N_NODES + N_EDGESC) * sizeof(int), stream);
  deg_kernel<<<(N_INC + 255) / 256, 256, 0, stream>>>(e_nodes, e_edges, DN, DE);
  scan_kernel<<<1, 256, 0, stream>>>(DE, OFF);
  nscan_kernel<<<1, 1024, 0, stream>>>(DN, NOFF, CUR);
  bucket_kernel<<<(N_INC + 255) / 256, 256, 0, stream>>>(e_nodes, e_edges, CUR, INCN);

  // 1 wave (16 nodes) per block -> 3125 blocks
  gru_mfma_kernel<<<N_NODES / 16, 64, 0, stream>>>(
      price, w_ih, w_hh, b_ih, b_hh, Y);

  // conv1: node->edge (+theta1), edge->node CSR gather (+bias1+leaky)
  edge_gather_kernel<<<N_EDGESC, 256, 0, stream>>>(Y, e_nodes, OFF, theta1, EF);
  node_gather_kernel<<<(N_NODES * 8 + 255) / 256, 256, 0, stream>>>(EF, NOFF, INCN, bias1, Y);

  // conv2: node->edge (+theta2), edge->node CSR gather (+bias2+leaky+w_out+b_out)
  edge_gather_kernel<<<N_EDGESC, 256, 0, stream>>>(Y, e_nodes, OFF, theta2, EF);
  node_gather_out_kernel<<<(N_NODES * 8 + 255) / 256, 256, 0, stream>>>(
      EF, NOFF, INCN, bias2, w_out, b_out, out);
}

// Round 12
// 373.669 us; speedup vs baseline: 1.0153x; 1.0153x over previous
//
#include <hip/hip_runtime.h>
#include <math.h>

#define N_NODES 50000
#define N_EDGESC 2000
#define N_INC   200000
#define SEQ     64
#define FEATN   6
#define CH      32
#define OUTF    5
#define SLOPE   0.01f
#define XS_STR  52   // padded LDS stride (floats): 16B-aligned rows, 2-way banks

typedef __attribute__((ext_vector_type(8))) short bf16x8;
typedef __attribute__((ext_vector_type(4))) float f32x4;

__device__ __forceinline__ float fast_rcp(float x) { return __builtin_amdgcn_rcpf(x); }
__device__ __forceinline__ float sigm(float x) { return fast_rcp(1.f + __expf(-x)); }
__device__ __forceinline__ float tanh_fast(float x) { return 1.f - 2.f * fast_rcp(1.f + __expf(2.f * x)); }
__device__ __forceinline__ float leaky(float v) { return v > 0.f ? v : SLOPE * v; }

__device__ __forceinline__ ushort f2bf(float x) {
  uint u = __float_as_uint(x);
  u = u + 0x7fffu + ((u >> 16) & 1u);
  return (ushort)(u >> 16);
}
__device__ __forceinline__ float bf2f(ushort s) {
  return __uint_as_float(((uint)s) << 16);
}
__device__ __forceinline__ uint pk_bf16(float a, float b) {
  uint r;
  asm("v_cvt_pk_bf16_f32 %0, %1, %2" : "=v"(r) : "v"(a), "v"(b));
  return r;
}

union BW { bf16x8 v; uint w[4]; uint2 d[2]; };

// ---------------- GRU via MFMA: one 64-thread block = one wave = 16 nodes ----------------
// Round-12: x-load latency fix.  Round-11 counters showed gru dur ~= time to
// stream price at 208 GB/s (FETCH 37.7MB): per-step 8B loads at 1536B stride,
// 1-step prefetch, ~1.3 waves/SIMD -> HBM-latency-bound.  Now price is staged
// per 8-step chunk: coalesced dwordx4 loads issued at t%8==1 (T14 split),
// ds_write at t%8==7 (~4500 cycles of cover), double-buffered LDS, per-step x
// read from LDS.  Math bit-identical to round 11 (6.1e-5 known good).
__global__ __launch_bounds__(64) void gru_mfma_kernel(
    const float* __restrict__ price,
    const float* __restrict__ w_ih, const float* __restrict__ w_hh,
    const float* __restrict__ b_ih, const float* __restrict__ b_hh,
    float* __restrict__ Y)
{
  __shared__ __align__(16) ushort Hh[16 * 40];
  __shared__ __align__(16) ushort Hl[16 * 40];
  __shared__ __align__(16) float Xs[2][16 * XS_STR];

  const int lane = threadIdx.x & 63;
  const int q    = lane >> 4;   // k-group / D-row-quad
  const int m    = lane & 15;   // node-in-wave
  const int node = blockIdx.x * 16 + m;   // grid 3125*16 = 50000 exactly

  // staging lane mapping: 4 lanes per node, 16B piece each, 3 instrs/chunk
  const int nl = lane >> 2;
  const int pc = lane & 3;
  const float* xsrc = price + (blockIdx.x * 16 + nl) * (SEQ * FEATN);

  // ---- Whh A-frags (hi/lo split) ----
  bf16x8 WAhi[6], WAlo[6];
#pragma unroll
  for (int tt = 0; tt < 6; ++tt) {
    const float* wr = w_hh + (tt * 16 + m) * CH + 8 * q;
    float4 v0 = *(const float4*)(wr);
    float4 v1 = *(const float4*)(wr + 4);
    float vv[8] = {v0.x, v0.y, v0.z, v0.w, v1.x, v1.y, v1.z, v1.w};
#pragma unroll
    for (int e = 0; e < 8; ++e) {
      ushort h = f2bf(vv[e]);
      WAhi[tt][e] = (short)h;
      WAlo[tt][e] = (short)f2bf(vv[e] - bf2f(h));
    }
  }

  // ---- GI A-frags: K packing per gate-row g = 16*tt + m ----
  bf16x8 GA[6];
#pragma unroll
  for (int tt = 0; tt < 6; ++tt) {
    int g = tt * 16 + m;
    bf16x8 a = {0, 0, 0, 0, 0, 0, 0, 0};
    if (q < 3) {
      float w[6];
#pragma unroll
      for (int f = 0; f < FEATN; ++f) w[f] = w_ih[g * FEATN + f];
      ushort wh[6]; float wl[6];
#pragma unroll
      for (int f = 0; f < FEATN; ++f) { wh[f] = f2bf(w[f]); wl[f] = w[f] - bf2f(wh[f]); }
      if (q == 0) {
#pragma unroll
        for (int f = 0; f < 6; ++f) a[f] = (short)wh[f];
        a[6] = (short)wh[0]; a[7] = (short)wh[1];
      } else if (q == 1) {
#pragma unroll
        for (int f = 0; f < 4; ++f) a[f] = (short)wh[2 + f];
#pragma unroll
        for (int f = 0; f < 4; ++f) a[4 + f] = (short)f2bf(wl[f]);
      } else {
        a[0] = (short)f2bf(wl[4]);
        a[1] = (short)f2bf(wl[5]);
        float bias = b_ih[g] + (g < 64 ? b_hh[g] : 0.f);
        ushort bh = f2bf(bias);
        a[2] = (short)bh;
        a[3] = (short)f2bf(bias - bf2f(bh));
      }
    }
    GA[tt] = a;
  }

  float bhn[8];
#pragma unroll
  for (int i = 0; i < 4; ++i) {
    bhn[i]     = b_hh[64 + 4 * q + i];
    bhn[4 + i] = b_hh[80 + 4 * q + i];
  }

  {
    uint2 z; z.x = 0; z.y = 0;
    *(uint2*)(Hh + m * 40 + 4 * q) = z;
    *(uint2*)(Hh + m * 40 + 16 + 4 * q) = z;
    *(uint2*)(Hl + m * 40 + 4 * q) = z;
    *(uint2*)(Hl + m * 40 + 16 + 4 * q) = z;
  }

  float h_f32[8];
#pragma unroll
  for (int i = 0; i < 8; ++i) h_f32[i] = 0.f;

  // ---- stage chunk 0 (cold start: load + write immediately) ----
  float4 xb0, xb1, xb2;
  {
    const float* s = xsrc;  // chunk 0 at float offset 0
    xb0 = *(const float4*)(s + pc * 4);
    xb1 = *(const float4*)(s + 16 + pc * 4);
    xb2 = *(const float4*)(s + 32 + pc * 4);
    float* d = &Xs[0][nl * XS_STR];
    *(float4*)(d + pc * 4) = xb0;
    *(float4*)(d + 16 + pc * 4) = xb1;
    *(float4*)(d + 32 + pc * 4) = xb2;
  }

  const f32x4 zz = {0.f, 0.f, 0.f, 0.f};

#pragma unroll 8
  for (int t = 0; t < SEQ; ++t) {
    const int ch = t >> 3;

    // T14 split: issue next chunk's loads early in this chunk...
    if ((t & 7) == 1 && ch < 7) {
      const float* s = xsrc + (ch + 1) * 48;
      xb0 = *(const float4*)(s + pc * 4);
      xb1 = *(const float4*)(s + 16 + pc * 4);
      xb2 = *(const float4*)(s + 32 + pc * 4);
    }
    // ...and commit to the other LDS buffer at the end of the chunk.
    if ((t & 7) == 7 && ch < 7) {
      float* d = &Xs[(ch + 1) & 1][nl * XS_STR];
      *(float4*)(d + pc * 4) = xb0;
      *(float4*)(d + 16 + pc * 4) = xb1;
      *(float4*)(d + 32 + pc * 4) = xb2;
    }

    // per-step x from LDS (broadcast within each node's 4-lane group)
    const float* xr = &Xs[ch & 1][m * XS_STR + (t & 7) * 6];
    float2 x01 = *(const float2*)(xr);
    float2 x23 = *(const float2*)(xr + 2);
    float2 x45 = *(const float2*)(xr + 4);
    float xc0 = x01.x, xc1 = x01.y, xc2 = x23.x, xc3 = x23.y, xc4 = x45.x, xc5 = x45.y;

    // ---- build x B-frag via packed cvt (hi/lo split), guarded as in r6/r7 ----
    BW bx; bx.w[0] = 0; bx.w[1] = 0; bx.w[2] = 0; bx.w[3] = 0;
    if (q < 3) {
      uint p01 = pk_bf16(xc0, xc1);
      uint p23 = pk_bf16(xc2, xc3);
      uint p45 = pk_bf16(xc4, xc5);
      float l0 = xc0 - __uint_as_float(p01 << 16);
      float l1 = xc1 - __uint_as_float(p01 & 0xFFFF0000u);
      float l2 = xc2 - __uint_as_float(p23 << 16);
      float l3 = xc3 - __uint_as_float(p23 & 0xFFFF0000u);
      float l4 = xc4 - __uint_as_float(p45 << 16);
      float l5 = xc5 - __uint_as_float(p45 & 0xFFFF0000u);
      if (q == 0) {
        bx.w[0] = p01; bx.w[1] = p23; bx.w[2] = p45;
        bx.w[3] = pk_bf16(l0, l1);
      } else if (q == 1) {
        bx.w[0] = pk_bf16(l2, l3); bx.w[1] = pk_bf16(l4, l5);
        bx.w[2] = p01; bx.w[3] = p23;
      } else {
        bx.w[0] = p45; bx.w[1] = 0x3F803F80u;
      }
    }
    bf16x8 Bx = bx.v;

    // ---- H B-frags from LDS ----
    bf16x8 HhF = *(bf16x8*)(Hh + m * 40 + 8 * q);
    bf16x8 HlF = *(bf16x8*)(Hl + m * 40 + 8 * q);

    // ---- MFMAs (builtins: hazard-safe lowering) ----
    f32x4 aRZ[4], aNh[2], aNi[2];
#pragma unroll
    for (int tt = 0; tt < 4; ++tt) {
      f32x4 a = __builtin_amdgcn_mfma_f32_16x16x32_bf16(GA[tt], Bx, zz, 0, 0, 0);
      a = __builtin_amdgcn_mfma_f32_16x16x32_bf16(WAlo[tt], HhF, a, 0, 0, 0);
      a = __builtin_amdgcn_mfma_f32_16x16x32_bf16(WAhi[tt], HlF, a, 0, 0, 0);
      a = __builtin_amdgcn_mfma_f32_16x16x32_bf16(WAhi[tt], HhF, a, 0, 0, 0);
      aRZ[tt] = a;
    }
#pragma unroll
    for (int tt = 0; tt < 2; ++tt) {
      f32x4 a = __builtin_amdgcn_mfma_f32_16x16x32_bf16(WAlo[4 + tt], HhF, zz, 0, 0, 0);
      a = __builtin_amdgcn_mfma_f32_16x16x32_bf16(WAhi[4 + tt], HlF, a, 0, 0, 0);
      a = __builtin_amdgcn_mfma_f32_16x16x32_bf16(WAhi[4 + tt], HhF, a, 0, 0, 0);
      aNh[tt] = a;
      aNi[tt] = __builtin_amdgcn_mfma_f32_16x16x32_bf16(GA[4 + tt], Bx, zz, 0, 0, 0);
    }

    // ---- gates + h-update (lane-local) ----
    float hv[8];
#pragma unroll
    for (int s = 0; s < 2; ++s) {
#pragma unroll
      for (int i = 0; i < 4; ++i) {
        int u = s * 4 + i;
        float r  = sigm(aRZ[s][i]);
        float z  = sigm(aRZ[2 + s][i]);
        float n  = tanh_fast(aNi[s][i] + r * (aNh[s][i] + bhn[u]));
        float h2 = n + z * (h_f32[u] - n);
        h_f32[u] = h2;
        hv[u] = h2;
      }
    }

    // ---- packed H writeback (hi + lo), dword stores ----
    uint ph0 = pk_bf16(hv[0], hv[1]);
    uint ph1 = pk_bf16(hv[2], hv[3]);
    uint ph2 = pk_bf16(hv[4], hv[5]);
    uint ph3 = pk_bf16(hv[6], hv[7]);
    float e0 = hv[0] - __uint_as_float(ph0 << 16);
    float e1 = hv[1] - __uint_as_float(ph0 & 0xFFFF0000u);
    float e2 = hv[2] - __uint_as_float(ph1 << 16);
    float e3 = hv[3] - __uint_as_float(ph1 & 0xFFFF0000u);
    float e4 = hv[4] - __uint_as_float(ph2 << 16);
    float e5 = hv[5] - __uint_as_float(ph2 & 0xFFFF0000u);
    float e6 = hv[6] - __uint_as_float(ph3 << 16);
    float e7 = hv[7] - __uint_as_float(ph3 & 0xFFFF0000u);
    uint2 wa, wb;
    wa.x = ph0; wa.y = ph1; wb.x = ph2; wb.y = ph3;
    *(uint2*)(Hh + m * 40 + 4 * q) = wa;
    *(uint2*)(Hh + m * 40 + 16 + 4 * q) = wb;
    wa.x = pk_bf16(e0, e1); wa.y = pk_bf16(e2, e3);
    wb.x = pk_bf16(e4, e5); wb.y = pk_bf16(e6, e7);
    *(uint2*)(Hl + m * 40 + 4 * q) = wa;
    *(uint2*)(Hl + m * 40 + 16 + 4 * q) = wb;
  }

  // ---- epilogue: coalesced Y write, h = hi + lo from LDS ----
  {
    int mm = lane >> 2, c = lane & 3;
    int onode = blockIdx.x * 16 + mm;
    bf16x8 vh = *(bf16x8*)(Hh + mm * 40 + c * 8);
    bf16x8 vl = *(bf16x8*)(Hl + mm * 40 + c * 8);
    float o[8];
#pragma unroll
    for (int e = 0; e < 8; ++e) o[e] = bf2f((ushort)vh[e]) + bf2f((ushort)vl[e]);
    float4 o0; o0.x = o[0]; o0.y = o[1]; o0.z = o[2]; o0.w = o[3];
    float4 o1; o1.x = o[4]; o1.y = o[5]; o1.z = o[6]; o1.w = o[7];
    *(float4*)(Y + onode * CH + c * 8) = o0;
    *(float4*)(Y + onode * CH + c * 8 + 4) = o1;
  }
}

// ---------------- degree counting ----------------
__global__ __launch_bounds__(256) void deg_kernel(
    const int* __restrict__ nodes, const int* __restrict__ edges,
    int* __restrict__ DN, int* __restrict__ DE)
{
  int i = blockIdx.x * 256 + threadIdx.x;
  if (i < N_INC) {
    atomicAdd(&DN[nodes[i]], 1);
    atomicAdd(&DE[edges[i]], 1);
  }
}

// ---------------- exclusive scan of edge degrees (single block, 2000) ----------------
__global__ __launch_bounds__(256) void scan_kernel(const int* __restrict__ DE, int* __restrict__ OFF)
{
  __shared__ int part[256];
  int t = threadIdx.x;
  int c[8]; int sum = 0;
#pragma unroll
  for (int u = 0; u < 8; ++u) {
    int idx = t * 8 + u;
    int x = (idx < N_EDGESC) ? DE[idx] : 0;
    c[u] = x; sum += x;
  }
  part[t] = sum;
  __syncthreads();
  for (int d = 1; d < 256; d <<= 1) {
    int v = (t >= d) ? part[t - d] : 0;
    __syncthreads();
    part[t] += v;
    __syncthreads();
  }
  int base = part[t] - sum;
#pragma unroll
  for (int u = 0; u < 8; ++u) {
    int idx = t * 8 + u;
    if (idx <= N_EDGESC) OFF[idx] = base;
    base += c[u];
  }
}

// ---------------- exclusive scan of node degrees (single block 1024, 50000) ----------------
#define NPER 49  // 1024*49 >= 50000
__global__ __launch_bounds__(1024) void nscan_kernel(
    const int* __restrict__ DN, int* __restrict__ NOFF, int* __restrict__ CUR)
{
  __shared__ int part[1024];
  int t = threadIdx.x;
  int cl[NPER]; int sum = 0;
  int base_i = t * NPER;
#pragma unroll
  for (int u = 0; u < NPER; ++u) {
    int idx = base_i + u;
    int x = (idx < N_NODES) ? DN[idx] : 0;
    cl[u] = x; sum += x;
  }
  part[t] = sum;
  __syncthreads();
  for (int d = 1; d < 1024; d <<= 1) {
    int v = (t >= d) ? part[t - d] : 0;
    __syncthreads();
    part[t] += v;
    __syncthreads();
  }
  int run = part[t] - sum;  // exclusive
#pragma unroll
  for (int u = 0; u < NPER; ++u) {
    int idx = base_i + u;
    if (idx < N_NODES) { NOFF[idx] = run; CUR[idx] = run; }
    run += cl[u];
  }
  if (t == 1023) NOFF[N_NODES] = run;
}

// ---------------- bucket incidences by node: INCN[pos] = edge ----------------
__global__ __launch_bounds__(256) void bucket_kernel(
    const int* __restrict__ nodes, const int* __restrict__ edges,
    int* __restrict__ CUR, int* __restrict__ INCN)
{
  int i = blockIdx.x * 256 + threadIdx.x;
  if (i < N_INC) {
    int p = atomicAdd(&CUR[nodes[i]], 1);
    INCN[p] = edges[i];
  }
}

// ---------------- node->edge gather-sum + fused theta (256 thr, 2-way ILP) ----------------
__global__ __launch_bounds__(256) void edge_gather_kernel(
    const float* __restrict__ X, const int* __restrict__ nodes,
    const int* __restrict__ OFF, const float* __restrict__ theta,
    float* __restrict__ EF)
{
  int e = blockIdx.x;
  int s = OFF[e], tE = OFF[e + 1];
  int f = threadIdx.x & 31, g = threadIdx.x >> 5;  // 8 row-groups
  float a0 = 0.f, a1 = 0.f;
  for (int i = s + g; i < tE; i += 16) {
    a0 += X[nodes[i] * CH + f];
    if (i + 8 < tE) a1 += X[nodes[i + 8] * CH + f];
  }
  __shared__ float red[8][33];
  __shared__ __align__(16) float e32[32];
  red[g][f] = a0 + a1;
  __syncthreads();
  if (threadIdx.x < 32) {
    float acc = 0.f;
#pragma unroll
    for (int r = 0; r < 8; ++r) acc += red[r][f];
    int cnt = tE - s;
    float binv = cnt > 0 ? 1.f / (float)cnt : 0.f;
    e32[f] = acc * binv;
    float s0 = 0.f, s1 = 0.f;
#pragma unroll
    for (int k4 = 0; k4 < 8; ++k4) {
      float4 ev = *(float4*)(e32 + 4 * k4);
      float4 tv = *(const float4*)(theta + f * CH + 4 * k4);
      s0 += tv.x * ev.x + tv.z * ev.z;
      s1 += tv.y * ev.y + tv.w * ev.w;
    }
    EF[e * CH + f] = s0 + s1;
  }
}

// ---------------- edge->node CSR gather + finalize (conv1) ----------------
__global__ __launch_bounds__(256) void node_gather_kernel(
    const float* __restrict__ EF, const int* __restrict__ NOFF,
    const int* __restrict__ INCN, const float* __restrict__ bias,
    float* __restrict__ X)
{
  int gid = blockIdx.x * 256 + threadIdx.x;
  if (gid >= N_NODES * 8) return;
  int n = gid >> 3, q = gid & 7;
  int s = NOFF[n], e = NOFF[n + 1];
  float4 acc = make_float4(0.f, 0.f, 0.f, 0.f);
  float4 acc2 = make_float4(0.f, 0.f, 0.f, 0.f);
  int k = s;
  for (; k + 1 < e; k += 2) {
    int e0 = INCN[k], e1 = INCN[k + 1];
    float4 v0 = *(const float4*)(EF + e0 * CH + q * 4);
    float4 v1 = *(const float4*)(EF + e1 * CH + q * 4);
    acc.x += v0.x; acc.y += v0.y; acc.z += v0.z; acc.w += v0.w;
    acc2.x += v1.x; acc2.y += v1.y; acc2.z += v1.z; acc2.w += v1.w;
  }
  if (k < e) {
    float4 v0 = *(const float4*)(EF + INCN[k] * CH + q * 4);
    acc.x += v0.x; acc.y += v0.y; acc.z += v0.z; acc.w += v0.w;
  }
  int d = e - s;
  float dinv = d > 0 ? 1.f / (float)d : 0.f;
  float4 b = *(const float4*)(bias + 4 * q);
  float4 o;
  o.x = leaky(fmaf(acc.x + acc2.x, dinv, b.x));
  o.y = leaky(fmaf(acc.y + acc2.y, dinv, b.y));
  o.z = leaky(fmaf(acc.z + acc2.z, dinv, b.z));
  o.w = leaky(fmaf(acc.w + acc2.w, dinv, b.w));
  *(float4*)(X + n * CH + 4 * q) = o;
}

// ---------------- edge->node CSR gather + finalize + output linear (conv2) ----------------
__global__ __launch_bounds__(256) void node_gather_out_kernel(
    const float* __restrict__ EF, const int* __restrict__ NOFF,
    const int* __restrict__ INCN, const float* __restrict__ bias,
    const float* __restrict__ w_out, const float* __restrict__ b_out,
    float* __restrict__ out)
{
  int gid = blockIdx.x * 256 + threadIdx.x;
  if (gid >= N_NODES * 8) return;
  int n = gid >> 3, q = gid & 7;
  int s = NOFF[n], e = NOFF[n + 1];
  float4 acc = make_float4(0.f, 0.f, 0.f, 0.f);
  float4 acc2 = make_float4(0.f, 0.f, 0.f, 0.f);
  int k = s;
  for (; k + 1 < e; k += 2) {
    int e0 = INCN[k], e1 = INCN[k + 1];
    float4 v0 = *(const float4*)(EF + e0 * CH + q * 4);
    float4 v1 = *(const float4*)(EF + e1 * CH + q * 4);
    acc.x += v0.x; acc.y += v0.y; acc.z += v0.z; acc.w += v0.w;
    acc2.x += v1.x; acc2.y += v1.y; acc2.z += v1.z; acc2.w += v1.w;
  }
  if (k < e) {
    float4 v0 = *(const float4*)(EF + INCN[k] * CH + q * 4);
    acc.x += v0.x; acc.y += v0.y; acc.z += v0.z; acc.w += v0.w;
  }
  int d = e - s;
  float dinv = d > 0 ? 1.f / (float)d : 0.f;
  float4 b = *(const float4*)(bias + 4 * q);
  float v0 = leaky(fmaf(acc.x + acc2.x, dinv, b.x));
  float v1 = leaky(fmaf(acc.y + acc2.y, dinv, b.y));
  float v2 = leaky(fmaf(acc.z + acc2.z, dinv, b.z));
  float v3 = leaky(fmaf(acc.w + acc2.w, dinv, b.w));

  float p[OUTF];
#pragma unroll
  for (int o = 0; o < OUTF; ++o) {
    const float* wr = w_out + o * CH + 4 * q;
    p[o] = v0 * wr[0] + v1 * wr[1] + v2 * wr[2] + v3 * wr[3];
  }
#pragma unroll
  for (int off = 1; off < 8; off <<= 1) {
#pragma unroll
    for (int o = 0; o < OUTF; ++o) p[o] += __shfl_xor(p[o], off);
  }
  if (q < OUTF) out[n * OUTF + q] = leaky(p[q] + b_out[q]);
}

extern "C" void kernel_launch(void* const* d_in, const int* in_sizes, int n_in,
                              void* d_out, int out_size, void* d_ws, size_t ws_size,
                              hipStream_t stream)
{
  const float* price   = (const float*)d_in[0];
  const int*   e_nodes = (const int*)d_in[1];
  const int*   e_edges = (const int*)d_in[2];
  const float* w_ih    = (const float*)d_in[6];
  const float* w_hh    = (const float*)d_in[7];
  const float* b_ih    = (const float*)d_in[8];
  const float* b_hh    = (const float*)d_in[9];
  const float* theta1  = (const float*)d_in[10];
  const float* bias1   = (const float*)d_in[11];
  const float* theta2  = (const float*)d_in[12];
  const float* bias2   = (const float*)d_in[13];
  const float* w_out   = (const float*)d_in[14];
  const float* b_out   = (const float*)d_in[15];
  float* out = (float*)d_out;

  float* ws   = (float*)d_ws;
  float* Y    = ws;                    // [50000*32]
  float* EF   = ws + 1600000;          // [2000*32]
  int*   DN   = (int*)(ws + 1664000);  // [50000]
  int*   DE   = DN + N_NODES;          // [2000]
  int*   OFF  = DE + N_EDGESC;         // [2001]
  int*   NOFF = OFF + N_EDGESC + 1;    // [50001]
  int*   CUR  = NOFF + N_NODES + 1;    // [50000]
  int*   INCN = CUR + N_NODES;         // [200000]

  hipMemsetAsync(DN, 0, (N_NODES + N_EDGESC) * sizeof(int), stream);
  deg_kernel<<<(N_INC + 255) / 256, 256, 0, stream>>>(e_nodes, e_edges, DN, DE);
  scan_kernel<<<1, 256, 0, stream>>>(DE, OFF);
  nscan_kernel<<<1, 1024, 0, stream>>>(DN, NOFF, CUR);
  bucket_kernel<<<(N_INC + 255) / 256, 256, 0, stream>>>(e_nodes, e_edges, CUR, INCN);

  // 1 wave (16 nodes) per block -> 3125 blocks
  gru_mfma_kernel<<<N_NODES / 16, 64, 0, stream>>>(
      price, w_ih, w_hh, b_ih, b_hh, Y);

  // conv1: node->edge (+theta1), edge->node CSR gather (+bias1+leaky)
  edge_gather_kernel<<<N_EDGESC, 256, 0, stream>>>(Y, e_nodes, OFF, theta1, EF);
  node_gather_kernel<<<(N_NODES * 8 + 255) / 256, 256, 0, stream>>>(EF, NOFF, INCN, bias1, Y);

  // conv2: node->edge (+theta2), edge->node CSR gather (+bias2+leaky+w_out+b_out)
  edge_gather_kernel<<<N_EDGESC, 256, 0, stream>>>(Y, e_nodes, OFF, theta2, EF);
  node_gather_out_kernel<<<(N_NODES * 8 + 255) / 256, 256, 0, stream>>>(
      EF, NOFF, INCN, bias2, w_out, b_out, out);
}

// Round 13
// 369.306 us; speedup vs baseline: 1.0273x; 1.0118x over previous
//
#include <hip/hip_runtime.h>
#include <math.h>

#define N_NODES 50000
#define N_EDGESC 2000
#define N_INC   200000
#define SEQ     64
#define FEATN   6
#define CH      32
#define OUTF    5
#define SLOPE   0.01f

typedef __attribute__((ext_vector_type(8))) short bf16x8;
typedef __attribute__((ext_vector_type(4))) float f32x4;

__device__ __forceinline__ float fast_rcp(float x) { return __builtin_amdgcn_rcpf(x); }
__device__ __forceinline__ float sigm(float x) { return fast_rcp(1.f + __expf(-x)); }
__device__ __forceinline__ float tanh_fast(float x) { return 1.f - 2.f * fast_rcp(1.f + __expf(2.f * x)); }
__device__ __forceinline__ float leaky(float v) { return v > 0.f ? v : SLOPE * v; }

__device__ __forceinline__ ushort f2bf(float x) {
  uint u = __float_as_uint(x);
  u = u + 0x7fffu + ((u >> 16) & 1u);
  return (ushort)(u >> 16);
}
__device__ __forceinline__ float bf2f(ushort s) {
  return __uint_as_float(((uint)s) << 16);
}
__device__ __forceinline__ uint pk_bf16(float a, float b) {
  uint r;
  asm("v_cvt_pk_bf16_f32 %0, %1, %2" : "=v"(r) : "v"(a), "v"(b));
  return r;
}

union BW { bf16x8 v; uint w[4]; uint2 d[2]; };

// ---------------- GRU via MFMA: one wave = TWO independent 16-node chains ----------------
// Round-13: in-wave ILP.  Rounds 5-12 pinned the GRU at ~215us with VALUBusy
// ~48%, MfmaUtil ~15%, ~1.3 waves/SIMD: ~40% of issue slots idle on the
// serial chain (ds_read H -> 4-deep MFMA -> 2 serial trans -> ds_write).
// Two independent chains per wave (nodes m and m+16, shared weight frags)
// give the scheduler a second instruction stream to fill those stalls.
// Per-chain math bit-identical to round 11 (6.1e-5 known good).
__global__ __launch_bounds__(64) void gru_mfma_kernel(
    const float* __restrict__ price,
    const float* __restrict__ w_ih, const float* __restrict__ w_hh,
    const float* __restrict__ b_ih, const float* __restrict__ b_hh,
    float* __restrict__ Y)
{
  __shared__ __align__(16) ushort HhA[16 * 40];
  __shared__ __align__(16) ushort HlA[16 * 40];
  __shared__ __align__(16) ushort HhB[16 * 40];
  __shared__ __align__(16) ushort HlB[16 * 40];

  const int lane = threadIdx.x & 63;
  const int q    = lane >> 4;   // k-group / D-row-quad
  const int m    = lane & 15;   // node-in-chain
  const int nodeA = blockIdx.x * 32 + m;
  const int nodeB = nodeA + 16;
  const int nodeAC = nodeA < N_NODES ? nodeA : 0;
  const int nodeBC = nodeB < N_NODES ? nodeB : 0;

  // ---- Whh A-frags (hi/lo split) — shared by both chains ----
  bf16x8 WAhi[6], WAlo[6];
#pragma unroll
  for (int tt = 0; tt < 6; ++tt) {
    const float* wr = w_hh + (tt * 16 + m) * CH + 8 * q;
    float4 v0 = *(const float4*)(wr);
    float4 v1 = *(const float4*)(wr + 4);
    float vv[8] = {v0.x, v0.y, v0.z, v0.w, v1.x, v1.y, v1.z, v1.w};
#pragma unroll
    for (int e = 0; e < 8; ++e) {
      ushort h = f2bf(vv[e]);
      WAhi[tt][e] = (short)h;
      WAlo[tt][e] = (short)f2bf(vv[e] - bf2f(h));
    }
  }

  // ---- GI A-frags: K packing per gate-row g = 16*tt + m ----
  bf16x8 GA[6];
#pragma unroll
  for (int tt = 0; tt < 6; ++tt) {
    int g = tt * 16 + m;
    bf16x8 a = {0, 0, 0, 0, 0, 0, 0, 0};
    if (q < 3) {
      float w[6];
#pragma unroll
      for (int f = 0; f < FEATN; ++f) w[f] = w_ih[g * FEATN + f];
      ushort wh[6]; float wl[6];
#pragma unroll
      for (int f = 0; f < FEATN; ++f) { wh[f] = f2bf(w[f]); wl[f] = w[f] - bf2f(wh[f]); }
      if (q == 0) {
#pragma unroll
        for (int f = 0; f < 6; ++f) a[f] = (short)wh[f];
        a[6] = (short)wh[0]; a[7] = (short)wh[1];
      } else if (q == 1) {
#pragma unroll
        for (int f = 0; f < 4; ++f) a[f] = (short)wh[2 + f];
#pragma unroll
        for (int f = 0; f < 4; ++f) a[4 + f] = (short)f2bf(wl[f]);
      } else {
        a[0] = (short)f2bf(wl[4]);
        a[1] = (short)f2bf(wl[5]);
        float bias = b_ih[g] + (g < 64 ? b_hh[g] : 0.f);
        ushort bh = f2bf(bias);
        a[2] = (short)bh;
        a[3] = (short)f2bf(bias - bf2f(bh));
      }
    }
    GA[tt] = a;
  }

  float bhn[8];
#pragma unroll
  for (int i = 0; i < 4; ++i) {
    bhn[i]     = b_hh[64 + 4 * q + i];
    bhn[4 + i] = b_hh[80 + 4 * q + i];
  }

  {
    uint2 z; z.x = 0; z.y = 0;
    *(uint2*)(HhA + m * 40 + 4 * q) = z;
    *(uint2*)(HhA + m * 40 + 16 + 4 * q) = z;
    *(uint2*)(HlA + m * 40 + 4 * q) = z;
    *(uint2*)(HlA + m * 40 + 16 + 4 * q) = z;
    *(uint2*)(HhB + m * 40 + 4 * q) = z;
    *(uint2*)(HhB + m * 40 + 16 + 4 * q) = z;
    *(uint2*)(HlB + m * 40 + 4 * q) = z;
    *(uint2*)(HlB + m * 40 + 16 + 4 * q) = z;
  }

  float hA[8], hB[8];
#pragma unroll
  for (int i = 0; i < 8; ++i) { hA[i] = 0.f; hB[i] = 0.f; }

  const float* xpA = price + nodeAC * (SEQ * FEATN);
  const float* xpB = price + nodeBC * (SEQ * FEATN);
  float xcA[6], xnA[6], xcB[6], xnB[6];
  if (q < 3) {
    float2 a0 = *(const float2*)(xpA);
    float2 a1 = *(const float2*)(xpA + 2);
    float2 a2 = *(const float2*)(xpA + 4);
    xcA[0] = a0.x; xcA[1] = a0.y; xcA[2] = a1.x; xcA[3] = a1.y; xcA[4] = a2.x; xcA[5] = a2.y;
    float2 b0 = *(const float2*)(xpB);
    float2 b1 = *(const float2*)(xpB + 2);
    float2 b2 = *(const float2*)(xpB + 4);
    xcB[0] = b0.x; xcB[1] = b0.y; xcB[2] = b1.x; xcB[3] = b1.y; xcB[4] = b2.x; xcB[5] = b2.y;
  }

  const f32x4 zz = {0.f, 0.f, 0.f, 0.f};

  for (int t = 0; t < SEQ; ++t) {
    // ---- build both x B-frags (hi/lo split) ----
    BW bxA; bxA.w[0] = 0; bxA.w[1] = 0; bxA.w[2] = 0; bxA.w[3] = 0;
    BW bxB; bxB.w[0] = 0; bxB.w[1] = 0; bxB.w[2] = 0; bxB.w[3] = 0;
    if (q < 3) {
      {
        uint p01 = pk_bf16(xcA[0], xcA[1]);
        uint p23 = pk_bf16(xcA[2], xcA[3]);
        uint p45 = pk_bf16(xcA[4], xcA[5]);
        float l0 = xcA[0] - __uint_as_float(p01 << 16);
        float l1 = xcA[1] - __uint_as_float(p01 & 0xFFFF0000u);
        float l2 = xcA[2] - __uint_as_float(p23 << 16);
        float l3 = xcA[3] - __uint_as_float(p23 & 0xFFFF0000u);
        float l4 = xcA[4] - __uint_as_float(p45 << 16);
        float l5 = xcA[5] - __uint_as_float(p45 & 0xFFFF0000u);
        if (q == 0) {
          bxA.w[0] = p01; bxA.w[1] = p23; bxA.w[2] = p45;
          bxA.w[3] = pk_bf16(l0, l1);
        } else if (q == 1) {
          bxA.w[0] = pk_bf16(l2, l3); bxA.w[1] = pk_bf16(l4, l5);
          bxA.w[2] = p01; bxA.w[3] = p23;
        } else {
          bxA.w[0] = p45; bxA.w[1] = 0x3F803F80u;
        }
      }
      {
        uint p01 = pk_bf16(xcB[0], xcB[1]);
        uint p23 = pk_bf16(xcB[2], xcB[3]);
        uint p45 = pk_bf16(xcB[4], xcB[5]);
        float l0 = xcB[0] - __uint_as_float(p01 << 16);
        float l1 = xcB[1] - __uint_as_float(p01 & 0xFFFF0000u);
        float l2 = xcB[2] - __uint_as_float(p23 << 16);
        float l3 = xcB[3] - __uint_as_float(p23 & 0xFFFF0000u);
        float l4 = xcB[4] - __uint_as_float(p45 << 16);
        float l5 = xcB[5] - __uint_as_float(p45 & 0xFFFF0000u);
        if (q == 0) {
          bxB.w[0] = p01; bxB.w[1] = p23; bxB.w[2] = p45;
          bxB.w[3] = pk_bf16(l0, l1);
        } else if (q == 1) {
          bxB.w[0] = pk_bf16(l2, l3); bxB.w[1] = pk_bf16(l4, l5);
          bxB.w[2] = p01; bxB.w[3] = p23;
        } else {
          bxB.w[0] = p45; bxB.w[1] = 0x3F803F80u;
        }
      }
    }
    bf16x8 BxA = bxA.v;
    bf16x8 BxB = bxB.v;

    // prefetch next step's x (both chains)
    if (t + 1 < SEQ && q < 3) {
      const float* nA = xpA + (t + 1) * FEATN;
      float2 a0 = *(const float2*)(nA);
      float2 a1 = *(const float2*)(nA + 2);
      float2 a2 = *(const float2*)(nA + 4);
      xnA[0] = a0.x; xnA[1] = a0.y; xnA[2] = a1.x; xnA[3] = a1.y; xnA[4] = a2.x; xnA[5] = a2.y;
      const float* nB = xpB + (t + 1) * FEATN;
      float2 b0 = *(const float2*)(nB);
      float2 b1 = *(const float2*)(nB + 2);
      float2 b2 = *(const float2*)(nB + 4);
      xnB[0] = b0.x; xnB[1] = b0.y; xnB[2] = b1.x; xnB[3] = b1.y; xnB[4] = b2.x; xnB[5] = b2.y;
    }

    // ---- H B-frags from LDS (both chains) ----
    bf16x8 HhFA = *(bf16x8*)(HhA + m * 40 + 8 * q);
    bf16x8 HlFA = *(bf16x8*)(HlA + m * 40 + 8 * q);
    bf16x8 HhFB = *(bf16x8*)(HhB + m * 40 + 8 * q);
    bf16x8 HlFB = *(bf16x8*)(HlB + m * 40 + 8 * q);

    // ---- MFMAs: two independent chains (scheduler interleaves) ----
    f32x4 aRZA[4], aNhA[2], aNiA[2];
    f32x4 aRZB[4], aNhB[2], aNiB[2];
#pragma unroll
    for (int tt = 0; tt < 4; ++tt) {
      f32x4 a = __builtin_amdgcn_mfma_f32_16x16x32_bf16(GA[tt], BxA, zz, 0, 0, 0);
      a = __builtin_amdgcn_mfma_f32_16x16x32_bf16(WAlo[tt], HhFA, a, 0, 0, 0);
      a = __builtin_amdgcn_mfma_f32_16x16x32_bf16(WAhi[tt], HlFA, a, 0, 0, 0);
      a = __builtin_amdgcn_mfma_f32_16x16x32_bf16(WAhi[tt], HhFA, a, 0, 0, 0);
      aRZA[tt] = a;
      f32x4 b = __builtin_amdgcn_mfma_f32_16x16x32_bf16(GA[tt], BxB, zz, 0, 0, 0);
      b = __builtin_amdgcn_mfma_f32_16x16x32_bf16(WAlo[tt], HhFB, b, 0, 0, 0);
      b = __builtin_amdgcn_mfma_f32_16x16x32_bf16(WAhi[tt], HlFB, b, 0, 0, 0);
      b = __builtin_amdgcn_mfma_f32_16x16x32_bf16(WAhi[tt], HhFB, b, 0, 0, 0);
      aRZB[tt] = b;
    }
#pragma unroll
    for (int tt = 0; tt < 2; ++tt) {
      f32x4 a = __builtin_amdgcn_mfma_f32_16x16x32_bf16(WAlo[4 + tt], HhFA, zz, 0, 0, 0);
      a = __builtin_amdgcn_mfma_f32_16x16x32_bf16(WAhi[4 + tt], HlFA, a, 0, 0, 0);
      a = __builtin_amdgcn_mfma_f32_16x16x32_bf16(WAhi[4 + tt], HhFA, a, 0, 0, 0);
      aNhA[tt] = a;
      aNiA[tt] = __builtin_amdgcn_mfma_f32_16x16x32_bf16(GA[4 + tt], BxA, zz, 0, 0, 0);
      f32x4 b = __builtin_amdgcn_mfma_f32_16x16x32_bf16(WAlo[4 + tt], HhFB, zz, 0, 0, 0);
      b = __builtin_amdgcn_mfma_f32_16x16x32_bf16(WAhi[4 + tt], HlFB, b, 0, 0, 0);
      b = __builtin_amdgcn_mfma_f32_16x16x32_bf16(WAhi[4 + tt], HhFB, b, 0, 0, 0);
      aNhB[tt] = b;
      aNiB[tt] = __builtin_amdgcn_mfma_f32_16x16x32_bf16(GA[4 + tt], BxB, zz, 0, 0, 0);
    }

    // ---- gates + h-update (both chains, independent) ----
    float hvA[8], hvB[8];
#pragma unroll
    for (int s = 0; s < 2; ++s) {
#pragma unroll
      for (int i = 0; i < 4; ++i) {
        int u = s * 4 + i;
        {
          float r  = sigm(aRZA[s][i]);
          float z  = sigm(aRZA[2 + s][i]);
          float n  = tanh_fast(aNiA[s][i] + r * (aNhA[s][i] + bhn[u]));
          float h2 = n + z * (hA[u] - n);
          hA[u] = h2; hvA[u] = h2;
        }
        {
          float r  = sigm(aRZB[s][i]);
          float z  = sigm(aRZB[2 + s][i]);
          float n  = tanh_fast(aNiB[s][i] + r * (aNhB[s][i] + bhn[u]));
          float h2 = n + z * (hB[u] - n);
          hB[u] = h2; hvB[u] = h2;
        }
      }
    }

    // ---- packed H writeback (both chains) ----
    {
      uint p0 = pk_bf16(hvA[0], hvA[1]);
      uint p1 = pk_bf16(hvA[2], hvA[3]);
      uint p2 = pk_bf16(hvA[4], hvA[5]);
      uint p3 = pk_bf16(hvA[6], hvA[7]);
      float e0 = hvA[0] - __uint_as_float(p0 << 16);
      float e1 = hvA[1] - __uint_as_float(p0 & 0xFFFF0000u);
      float e2 = hvA[2] - __uint_as_float(p1 << 16);
      float e3 = hvA[3] - __uint_as_float(p1 & 0xFFFF0000u);
      float e4 = hvA[4] - __uint_as_float(p2 << 16);
      float e5 = hvA[5] - __uint_as_float(p2 & 0xFFFF0000u);
      float e6 = hvA[6] - __uint_as_float(p3 << 16);
      float e7 = hvA[7] - __uint_as_float(p3 & 0xFFFF0000u);
      uint2 wa, wb;
      wa.x = p0; wa.y = p1; wb.x = p2; wb.y = p3;
      *(uint2*)(HhA + m * 40 + 4 * q) = wa;
      *(uint2*)(HhA + m * 40 + 16 + 4 * q) = wb;
      wa.x = pk_bf16(e0, e1); wa.y = pk_bf16(e2, e3);
      wb.x = pk_bf16(e4, e5); wb.y = pk_bf16(e6, e7);
      *(uint2*)(HlA + m * 40 + 4 * q) = wa;
      *(uint2*)(HlA + m * 40 + 16 + 4 * q) = wb;
    }
    {
      uint p0 = pk_bf16(hvB[0], hvB[1]);
      uint p1 = pk_bf16(hvB[2], hvB[3]);
      uint p2 = pk_bf16(hvB[4], hvB[5]);
      uint p3 = pk_bf16(hvB[6], hvB[7]);
      float e0 = hvB[0] - __uint_as_float(p0 << 16);
      float e1 = hvB[1] - __uint_as_float(p0 & 0xFFFF0000u);
      float e2 = hvB[2] - __uint_as_float(p1 << 16);
      float e3 = hvB[3] - __uint_as_float(p1 & 0xFFFF0000u);
      float e4 = hvB[4] - __uint_as_float(p2 << 16);
      float e5 = hvB[5] - __uint_as_float(p2 & 0xFFFF0000u);
      float e6 = hvB[6] - __uint_as_float(p3 << 16);
      float e7 = hvB[7] - __uint_as_float(p3 & 0xFFFF0000u);
      uint2 wa, wb;
      wa.x = p0; wa.y = p1; wb.x = p2; wb.y = p3;
      *(uint2*)(HhB + m * 40 + 4 * q) = wa;
      *(uint2*)(HhB + m * 40 + 16 + 4 * q) = wb;
      wa.x = pk_bf16(e0, e1); wa.y = pk_bf16(e2, e3);
      wb.x = pk_bf16(e4, e5); wb.y = pk_bf16(e6, e7);
      *(uint2*)(HlB + m * 40 + 4 * q) = wa;
      *(uint2*)(HlB + m * 40 + 16 + 4 * q) = wb;
    }

    if (q < 3) {
#pragma unroll
      for (int f = 0; f < 6; ++f) { xcA[f] = xnA[f]; xcB[f] = xnB[f]; }
    }
  }

  // ---- epilogue: coalesced Y writes, h = hi + lo from LDS ----
  {
    int mm = lane >> 2, c = lane & 3;
    int oA = blockIdx.x * 32 + mm;
    int oB = oA + 16;
    {
      bf16x8 vh = *(bf16x8*)(HhA + mm * 40 + c * 8);
      bf16x8 vl = *(bf16x8*)(HlA + mm * 40 + c * 8);
      float o[8];
#pragma unroll
      for (int e = 0; e < 8; ++e) o[e] = bf2f((ushort)vh[e]) + bf2f((ushort)vl[e]);
      if (oA < N_NODES) {
        float4 o0; o0.x = o[0]; o0.y = o[1]; o0.z = o[2]; o0.w = o[3];
        float4 o1; o1.x = o[4]; o1.y = o[5]; o1.z = o[6]; o1.w = o[7];
        *(float4*)(Y + oA * CH + c * 8) = o0;
        *(float4*)(Y + oA * CH + c * 8 + 4) = o1;
      }
    }
    {
      bf16x8 vh = *(bf16x8*)(HhB + mm * 40 + c * 8);
      bf16x8 vl = *(bf16x8*)(HlB + mm * 40 + c * 8);
      float o[8];
#pragma unroll
      for (int e = 0; e < 8; ++e) o[e] = bf2f((ushort)vh[e]) + bf2f((ushort)vl[e]);
      if (oB < N_NODES) {
        float4 o0; o0.x = o[0]; o0.y = o[1]; o0.z = o[2]; o0.w = o[3];
        float4 o1; o1.x = o[4]; o1.y = o[5]; o1.z = o[6]; o1.w = o[7];
        *(float4*)(Y + oB * CH + c * 8) = o0;
        *(float4*)(Y + oB * CH + c * 8 + 4) = o1;
      }
    }
  }
}

// ---------------- degree counting ----------------
__global__ __launch_bounds__(256) void deg_kernel(
    const int* __restrict__ nodes, const int* __restrict__ edges,
    int* __restrict__ DN, int* __restrict__ DE)
{
  int i = blockIdx.x * 256 + threadIdx.x;
  if (i < N_INC) {
    atomicAdd(&DN[nodes[i]], 1);
    atomicAdd(&DE[edges[i]], 1);
  }
}

// ---------------- exclusive scan of edge degrees (single block, 2000) ----------------
__global__ __launch_bounds__(256) void scan_kernel(const int* __restrict__ DE, int* __restrict__ OFF)
{
  __shared__ int part[256];
  int t = threadIdx.x;
  int c[8]; int sum = 0;
#pragma unroll
  for (int u = 0; u < 8; ++u) {
    int idx = t * 8 + u;
    int x = (idx < N_EDGESC) ? DE[idx] : 0;
    c[u] = x; sum += x;
  }
  part[t] = sum;
  __syncthreads();
  for (int d = 1; d < 256; d <<= 1) {
    int v = (t >= d) ? part[t - d] : 0;
    __syncthreads();
    part[t] += v;
    __syncthreads();
  }
  int base = part[t] - sum;
#pragma unroll
  for (int u = 0; u < 8; ++u) {
    int idx = t * 8 + u;
    if (idx <= N_EDGESC) OFF[idx] = base;
    base += c[u];
  }
}

// ---------------- exclusive scan of node degrees (single block 1024, 50000) ----------------
#define NPER 49  // 1024*49 >= 50000
__global__ __launch_bounds__(1024) void nscan_kernel(
    const int* __restrict__ DN, int* __restrict__ NOFF, int* __restrict__ CUR)
{
  __shared__ int part[1024];
  int t = threadIdx.x;
  int cl[NPER]; int sum = 0;
  int base_i = t * NPER;
#pragma unroll
  for (int u = 0; u < NPER; ++u) {
    int idx = base_i + u;
    int x = (idx < N_NODES) ? DN[idx] : 0;
    cl[u] = x; sum += x;
  }
  part[t] = sum;
  __syncthreads();
  for (int d = 1; d < 1024; d <<= 1) {
    int v = (t >= d) ? part[t - d] : 0;
    __syncthreads();
    part[t] += v;
    __syncthreads();
  }
  int run = part[t] - sum;  // exclusive
#pragma unroll
  for (int u = 0; u < NPER; ++u) {
    int idx = base_i + u;
    if (idx < N_NODES) { NOFF[idx] = run; CUR[idx] = run; }
    run += cl[u];
  }
  if (t == 1023) NOFF[N_NODES] = run;
}

// ---------------- bucket incidences by node: INCN[pos] = edge ----------------
__global__ __launch_bounds__(256) void bucket_kernel(
    const int* __restrict__ nodes, const int* __restrict__ edges,
    int* __restrict__ CUR, int* __restrict__ INCN)
{
  int i = blockIdx.x * 256 + threadIdx.x;
  if (i < N_INC) {
    int p = atomicAdd(&CUR[nodes[i]], 1);
    INCN[p] = edges[i];
  }
}

// ---------------- node->edge gather-sum + fused theta (256 thr, 2-way ILP) ----------------
__global__ __launch_bounds__(256) void edge_gather_kernel(
    const float* __restrict__ X, const int* __restrict__ nodes,
    const int* __restrict__ OFF, const float* __restrict__ theta,
    float* __restrict__ EF)
{
  int e = blockIdx.x;
  int s = OFF[e], tE = OFF[e + 1];
  int f = threadIdx.x & 31, g = threadIdx.x >> 5;  // 8 row-groups
  float a0 = 0.f, a1 = 0.f;
  for (int i = s + g; i < tE; i += 16) {
    a0 += X[nodes[i] * CH + f];
    if (i + 8 < tE) a1 += X[nodes[i + 8] * CH + f];
  }
  __shared__ float red[8][33];
  __shared__ __align__(16) float e32[32];
  red[g][f] = a0 + a1;
  __syncthreads();
  if (threadIdx.x < 32) {
    float acc = 0.f;
#pragma unroll
    for (int r = 0; r < 8; ++r) acc += red[r][f];
    int cnt = tE - s;
    float binv = cnt > 0 ? 1.f / (float)cnt : 0.f;
    e32[f] = acc * binv;
    float s0 = 0.f, s1 = 0.f;
#pragma unroll
    for (int k4 = 0; k4 < 8; ++k4) {
      float4 ev = *(float4*)(e32 + 4 * k4);
      float4 tv = *(const float4*)(theta + f * CH + 4 * k4);
      s0 += tv.x * ev.x + tv.z * ev.z;
      s1 += tv.y * ev.y + tv.w * ev.w;
    }
    EF[e * CH + f] = s0 + s1;
  }
}

// ---------------- edge->node CSR gather + finalize (conv1) ----------------
__global__ __launch_bounds__(256) void node_gather_kernel(
    const float* __restrict__ EF, const int* __restrict__ NOFF,
    const int* __restrict__ INCN, const float* __restrict__ bias,
    float* __restrict__ X)
{
  int gid = blockIdx.x * 256 + threadIdx.x;
  if (gid >= N_NODES * 8) return;
  int n = gid >> 3, q = gid & 7;
  int s = NOFF[n], e = NOFF[n + 1];
  float4 acc = make_float4(0.f, 0.f, 0.f, 0.f);
  float4 acc2 = make_float4(0.f, 0.f, 0.f, 0.f);
  int k = s;
  for (; k + 1 < e; k += 2) {
    int e0 = INCN[k], e1 = INCN[k + 1];
    float4 v0 = *(const float4*)(EF + e0 * CH + q * 4);
    float4 v1 = *(const float4*)(EF + e1 * CH + q * 4);
    acc.x += v0.x; acc.y += v0.y; acc.z += v0.z; acc.w += v0.w;
    acc2.x += v1.x; acc2.y += v1.y; acc2.z += v1.z; acc2.w += v1.w;
  }
  if (k < e) {
    float4 v0 = *(const float4*)(EF + INCN[k] * CH + q * 4);
    acc.x += v0.x; acc.y += v0.y; acc.z += v0.z; acc.w += v0.w;
  }
  int d = e - s;
  float dinv = d > 0 ? 1.f / (float)d : 0.f;
  float4 b = *(const float4*)(bias + 4 * q);
  float4 o;
  o.x = leaky(fmaf(acc.x + acc2.x, dinv, b.x));
  o.y = leaky(fmaf(acc.y + acc2.y, dinv, b.y));
  o.z = leaky(fmaf(acc.z + acc2.z, dinv, b.z));
  o.w = leaky(fmaf(acc.w + acc2.w, dinv, b.w));
  *(float4*)(X + n * CH + 4 * q) = o;
}

// ---------------- edge->node CSR gather + finalize + output linear (conv2) ----------------
__global__ __launch_bounds__(256) void node_gather_out_kernel(
    const float* __restrict__ EF, const int* __restrict__ NOFF,
    const int* __restrict__ INCN, const float* __restrict__ bias,
    const float* __restrict__ w_out, const float* __restrict__ b_out,
    float* __restrict__ out)
{
  int gid = blockIdx.x * 256 + threadIdx.x;
  if (gid >= N_NODES * 8) return;
  int n = gid >> 3, q = gid & 7;
  int s = NOFF[n], e = NOFF[n + 1];
  float4 acc = make_float4(0.f, 0.f, 0.f, 0.f);
  float4 acc2 = make_float4(0.f, 0.f, 0.f, 0.f);
  int k = s;
  for (; k + 1 < e; k += 2) {
    int e0 = INCN[k], e1 = INCN[k + 1];
    float4 v0 = *(const float4*)(EF + e0 * CH + q * 4);
    float4 v1 = *(const float4*)(EF + e1 * CH + q * 4);
    acc.x += v0.x; acc.y += v0.y; acc.z += v0.z; acc.w += v0.w;
    acc2.x += v1.x; acc2.y += v1.y; acc2.z += v1.z; acc2.w += v1.w;
  }
  if (k < e) {
    float4 v0 = *(const float4*)(EF + INCN[k] * CH + q * 4);
    acc.x += v0.x; acc.y += v0.y; acc.z += v0.z; acc.w += v0.w;
  }
  int d = e - s;
  float dinv = d > 0 ? 1.f / (float)d : 0.f;
  float4 b = *(const float4*)(bias + 4 * q);
  float v0 = leaky(fmaf(acc.x + acc2.x, dinv, b.x));
  float v1 = leaky(fmaf(acc.y + acc2.y, dinv, b.y));
  float v2 = leaky(fmaf(acc.z + acc2.z, dinv, b.z));
  float v3 = leaky(fmaf(acc.w + acc2.w, dinv, b.w));

  float p[OUTF];
#pragma unroll
  for (int o = 0; o < OUTF; ++o) {
    const float* wr = w_out + o * CH + 4 * q;
    p[o] = v0 * wr[0] + v1 * wr[1] + v2 * wr[2] + v3 * wr[3];
  }
#pragma unroll
  for (int off = 1; off < 8; off <<= 1) {
#pragma unroll
    for (int o = 0; o < OUTF; ++o) p[o] += __shfl_xor(p[o], off);
  }
  if (q < OUTF) out[n * OUTF + q] = leaky(p[q] + b_out[q]);
}

extern "C" void kernel_launch(void* const* d_in, const int* in_sizes, int n_in,
                              void* d_out, int out_size, void* d_ws, size_t ws_size,
                              hipStream_t stream)
{
  const float* price   = (const float*)d_in[0];
  const int*   e_nodes = (const int*)d_in[1];
  const int*   e_edges = (const int*)d_in[2];
  const float* w_ih    = (const float*)d_in[6];
  const float* w_hh    = (const float*)d_in[7];
  const float* b_ih    = (const float*)d_in[8];
  const float* b_hh    = (const float*)d_in[9];
  const float* theta1  = (const float*)d_in[10];
  const float* bias1   = (const float*)d_in[11];
  const float* theta2  = (const float*)d_in[12];
  const float* bias2   = (const float*)d_in[13];
  const float* w_out   = (const float*)d_in[14];
  const float* b_out   = (const float*)d_in[15];
  float* out = (float*)d_out;

  float* ws   = (float*)d_ws;
  float* Y    = ws;                    // [50000*32]
  float* EF   = ws + 1600000;          // [2000*32]
  int*   DN   = (int*)(ws + 1664000);  // [50000]
  int*   DE   = DN + N_NODES;          // [2000]
  int*   OFF  = DE + N_EDGESC;         // [2001]
  int*   NOFF = OFF + N_EDGESC + 1;    // [50001]
  int*   CUR  = NOFF + N_NODES + 1;    // [50000]
  int*   INCN = CUR + N_NODES;         // [200000]

  hipMemsetAsync(DN, 0, (N_NODES + N_EDGESC) * sizeof(int), stream);
  deg_kernel<<<(N_INC + 255) / 256, 256, 0, stream>>>(e_nodes, e_edges, DN, DE);
  scan_kernel<<<1, 256, 0, stream>>>(DE, OFF);
  nscan_kernel<<<1, 1024, 0, stream>>>(DN, NOFF, CUR);
  bucket_kernel<<<(N_INC + 255) / 256, 256, 0, stream>>>(e_nodes, e_edges, CUR, INCN);

  // 1 wave = 2 chains of 16 nodes -> 1563 blocks
  gru_mfma_kernel<<<(N_NODES + 31) / 32, 64, 0, stream>>>(
      price, w_ih, w_hh, b_ih, b_hh, Y);

  // conv1: node->edge (+theta1), edge->node CSR gather (+bias1+leaky)
  edge_gather_kernel<<<N_EDGESC, 256, 0, stream>>>(Y, e_nodes, OFF, theta1, EF);
  node_gather_kernel<<<(N_NODES * 8 + 255) / 256, 256, 0, stream>>>(EF, NOFF, INCN, bias1, Y);

  // conv2: node->edge (+theta2), edge->node CSR gather (+bias2+leaky+w_out+b_out)
  edge_gather_kernel<<<N_EDGESC, 256, 0, stream>>>(Y, e_nodes, OFF, theta2, EF);
  node_gather_out_kernel<<<(N_NODES * 8 + 255) / 256, 256, 0, stream>>>(
      EF, NOFF, INCN, bias2, w_out, b_out, out);
}

// Round 14
// 354.845 us; speedup vs baseline: 1.0692x; 1.0408x over previous
//
#include <hip/hip_runtime.h>
#include <math.h>

#define N_NODES 50000
#define N_EDGESC 2000
#define N_INC   200000
#define SEQ     64
#define FEATN   6
#define CH      32
#define OUTF    5
#define SLOPE   0.01f

typedef __attribute__((ext_vector_type(8))) short bf16x8;
typedef __attribute__((ext_vector_type(4))) float f32x4;
typedef __attribute__((ext_vector_type(16))) float f32x16;

__device__ __forceinline__ float fast_rcp(float x) { return __builtin_amdgcn_rcpf(x); }
__device__ __forceinline__ float sigm(float x) { return fast_rcp(1.f + __expf(-x)); }
__device__ __forceinline__ float tanh_fast(float x) { return 1.f - 2.f * fast_rcp(1.f + __expf(2.f * x)); }
__device__ __forceinline__ float leaky(float v) { return v > 0.f ? v : SLOPE * v; }

__device__ __forceinline__ ushort f2bf(float x) {
  uint u = __float_as_uint(x);
  u = u + 0x7fffu + ((u >> 16) & 1u);
  return (ushort)(u >> 16);
}
__device__ __forceinline__ float bf2f(ushort s) {
  return __uint_as_float(((uint)s) << 16);
}
__device__ __forceinline__ uint pk_bf16(float a, float b) {
  uint r;
  asm("v_cvt_pk_bf16_f32 %0, %1, %2" : "=v"(r) : "v"(a), "v"(b));
  return r;
}

union BW { bf16x8 v; uint w[4]; };

// ---------------- GRU via 32x32x16 MFMA: one wave = 32 nodes, H in-register ----------------
// Round-14: issue-bound fix.  r13 showed per-SIMD issue saturation (~85-90%:
// VALU 50 + MFMA 15 + trans ~15 + LDS); only instruction-count cuts help.
// 32x32x16 tiles: 24 MFMA sites (was 48, same FLOPs), and the verified C/D
// layout (col=lane&31, row=(reg&3)+8*(reg>>2)+4*(lane>>5)) puts each node's
// h across lane pair (l, l^32) -> H round-trip = 8 shfl_xor(,32), the LDS H
// buffers (and their 4.9M bank conflicts + latency) are GONE.
// A/B maps by analogy to the r5-proven 16x16x32: A row=lane&31, k=8*(lane>>5)+j;
// B col=lane&31, same k.  Numerics identical to r11/r13 (hi/lo split, same terms).
__global__ __launch_bounds__(64) void gru_mfma_kernel(
    const float* __restrict__ price,
    const float* __restrict__ w_ih, const float* __restrict__ w_hh,
    const float* __restrict__ b_ih, const float* __restrict__ b_hh,
    float* __restrict__ Y)
{
  __shared__ __align__(16) float Hfin[32 * 36];  // epilogue staging only

  const int lane = threadIdx.x & 63;
  const int c = lane & 31;       // node col / A row
  const int s = lane >> 5;       // K-half select
  const int node = blockIdx.x * 32 + c;
  const int nodeC = node < N_NODES ? node : N_NODES - 1;

  // ---- Whh A-frags: 3 gate tiles (r,z,n), rows g=T*32+c; A1: k=8s+j, A2: k=16+8s+j
  bf16x8 WA1hi[3], WA1lo[3], WA2hi[3], WA2lo[3];
#pragma unroll
  for (int T = 0; T < 3; ++T) {
    const float* wr = w_hh + (T * 32 + c) * CH;
    {
      const float* p = wr + 8 * s;
      float4 v0 = *(const float4*)(p);
      float4 v1 = *(const float4*)(p + 4);
      float vv[8] = {v0.x, v0.y, v0.z, v0.w, v1.x, v1.y, v1.z, v1.w};
#pragma unroll
      for (int e = 0; e < 8; ++e) {
        ushort h = f2bf(vv[e]);
        WA1hi[T][e] = (short)h;
        WA1lo[T][e] = (short)f2bf(vv[e] - bf2f(h));
      }
    }
    {
      const float* p = wr + 16 + 8 * s;
      float4 v0 = *(const float4*)(p);
      float4 v1 = *(const float4*)(p + 4);
      float vv[8] = {v0.x, v0.y, v0.z, v0.w, v1.x, v1.y, v1.z, v1.w};
#pragma unroll
      for (int e = 0; e < 8; ++e) {
        ushort h = f2bf(vv[e]);
        WA2hi[T][e] = (short)h;
        WA2lo[T][e] = (short)f2bf(vv[e] - bf2f(h));
      }
    }
  }

  // ---- GI A-frags: K packing k0-5 Whi*xhi | k6-11 Whi*xlo | k12,13 bias hi/lo*1
  //      GA2 (second GI product): k0-5 Wlo*xhi
  bf16x8 GA1[3], GA2[3];
#pragma unroll
  for (int T = 0; T < 3; ++T) {
    int g = T * 32 + c;
    float w[6]; ushort wh[6]; float wl[6];
#pragma unroll
    for (int f = 0; f < FEATN; ++f) w[f] = w_ih[g * FEATN + f];
#pragma unroll
    for (int f = 0; f < FEATN; ++f) { wh[f] = f2bf(w[f]); wl[f] = w[f] - bf2f(wh[f]); }
    bf16x8 a1 = {0, 0, 0, 0, 0, 0, 0, 0};
    bf16x8 a2 = {0, 0, 0, 0, 0, 0, 0, 0};
    if (s == 0) {
      // k0-7: {Whi0..5, Whi0, Whi1}  (k6,7 pair with xlo0,1)
#pragma unroll
      for (int f = 0; f < 6; ++f) a1[f] = (short)wh[f];
      a1[6] = (short)wh[0]; a1[7] = (short)wh[1];
      // GA2 k0-7: {Wlo0..5, 0, 0}
#pragma unroll
      for (int f = 0; f < 6; ++f) a2[f] = (short)f2bf(wl[f]);
    } else {
      // k8-15: {Whi2..5, bias_hi, bias_lo, 0, 0}
      a1[0] = (short)wh[2]; a1[1] = (short)wh[3];
      a1[2] = (short)wh[4]; a1[3] = (short)wh[5];
      float bias = b_ih[g] + (g < 64 ? b_hh[g] : 0.f);
      ushort bh = f2bf(bias);
      a1[4] = (short)bh;
      a1[5] = (short)f2bf(bias - bf2f(bh));
    }
    GA1[T] = a1; GA2[T] = a2;
  }

  // accNh C-init: b_hh n-gate values at this lane's D rows u(i)
  f32x16 bhnC, zz16;
#pragma unroll
  for (int i = 0; i < 16; ++i) {
    int u = (i & 3) + 8 * (i >> 2) + 4 * s;
    bhnC[i] = b_hh[64 + u];
    zz16[i] = 0.f;
  }

  float hst[16];
#pragma unroll
  for (int i = 0; i < 16; ++i) hst[i] = 0.f;

  const float* xp = price + nodeC * (SEQ * FEATN);

  for (int t = 0; t < SEQ; ++t) {
    // ---- x load + hi/lo split (both halves of a col do the same node) ----
    float2 x01 = *(const float2*)(xp + t * FEATN);
    float2 x23 = *(const float2*)(xp + t * FEATN + 2);
    float2 x45 = *(const float2*)(xp + t * FEATN + 4);
    uint p01 = pk_bf16(x01.x, x01.y);
    uint p23 = pk_bf16(x23.x, x23.y);
    uint p45 = pk_bf16(x45.x, x45.y);
    float l0 = x01.x - __uint_as_float(p01 << 16);
    float l1 = x01.y - __uint_as_float(p01 & 0xFFFF0000u);
    float l2 = x23.x - __uint_as_float(p23 << 16);
    float l3 = x23.y - __uint_as_float(p23 & 0xFFFF0000u);
    float l4 = x45.x - __uint_as_float(p45 << 16);
    float l5 = x45.y - __uint_as_float(p45 & 0xFFFF0000u);
    uint lo01 = pk_bf16(l0, l1);
    uint lo23 = pk_bf16(l2, l3);
    uint lo45 = pk_bf16(l4, l5);
    BW bx1, bx2;
    if (s == 0) {
      bx1.w[0] = p01; bx1.w[1] = p23; bx1.w[2] = p45; bx1.w[3] = lo01;
      bx2.w[0] = p01; bx2.w[1] = p23; bx2.w[2] = p45; bx2.w[3] = 0;
    } else {
      bx1.w[0] = lo23; bx1.w[1] = lo45; bx1.w[2] = 0x3F803F80u; bx1.w[3] = 0;
      bx2.w[0] = 0; bx2.w[1] = 0; bx2.w[2] = 0; bx2.w[3] = 0;
    }

    // ---- pack h_{t-1} -> bf16 hi/lo dwords (pairs of consecutive units) ----
    uint Dh[8], Dl[8];
#pragma unroll
    for (int k = 0; k < 8; ++k) {
      uint ph = pk_bf16(hst[2 * k], hst[2 * k + 1]);
      Dh[k] = ph;
      float e0 = hst[2 * k]     - __uint_as_float(ph << 16);
      float e1 = hst[2 * k + 1] - __uint_as_float(ph & 0xFFFF0000u);
      Dl[k] = pk_bf16(e0, e1);
    }
    // ---- in-register H exchange across lane^32 ----
    uint u0h = (uint)__shfl_xor((int)(s ? Dh[0] : Dh[2]), 32);
    uint u1h = (uint)__shfl_xor((int)(s ? Dh[1] : Dh[3]), 32);
    uint u2h = (uint)__shfl_xor((int)(s ? Dh[4] : Dh[6]), 32);
    uint u3h = (uint)__shfl_xor((int)(s ? Dh[5] : Dh[7]), 32);
    uint u0l = (uint)__shfl_xor((int)(s ? Dl[0] : Dl[2]), 32);
    uint u1l = (uint)__shfl_xor((int)(s ? Dl[1] : Dl[3]), 32);
    uint u2l = (uint)__shfl_xor((int)(s ? Dl[4] : Dl[6]), 32);
    uint u3l = (uint)__shfl_xor((int)(s ? Dl[5] : Dl[7]), 32);
    BW b1h, b2h, b1l, b2l;
    b1h.w[0] = s ? u0h : Dh[0]; b1h.w[1] = s ? u1h : Dh[1];
    b1h.w[2] = s ? Dh[2] : u0h; b1h.w[3] = s ? Dh[3] : u1h;
    b2h.w[0] = s ? u2h : Dh[4]; b2h.w[1] = s ? u3h : Dh[5];
    b2h.w[2] = s ? Dh[6] : u2h; b2h.w[3] = s ? Dh[7] : u3h;
    b1l.w[0] = s ? u0l : Dl[0]; b1l.w[1] = s ? u1l : Dl[1];
    b1l.w[2] = s ? Dl[2] : u0l; b1l.w[3] = s ? Dl[3] : u1l;
    b2l.w[0] = s ? u2l : Dl[4]; b2l.w[1] = s ? u3l : Dl[5];
    b2l.w[2] = s ? Dl[6] : u2l; b2l.w[3] = s ? Dl[7] : u3l;

    // ---- 24 MFMAs (builtins: hazard-safe) ----
    f32x16 aR = __builtin_amdgcn_mfma_f32_32x32x16_bf16(GA1[0], bx1.v, zz16, 0, 0, 0);
    aR = __builtin_amdgcn_mfma_f32_32x32x16_bf16(GA2[0], bx2.v, aR, 0, 0, 0);
    aR = __builtin_amdgcn_mfma_f32_32x32x16_bf16(WA1lo[0], b1h.v, aR, 0, 0, 0);
    aR = __builtin_amdgcn_mfma_f32_32x32x16_bf16(WA2lo[0], b2h.v, aR, 0, 0, 0);
    aR = __builtin_amdgcn_mfma_f32_32x32x16_bf16(WA1hi[0], b1l.v, aR, 0, 0, 0);
    aR = __builtin_amdgcn_mfma_f32_32x32x16_bf16(WA2hi[0], b2l.v, aR, 0, 0, 0);
    aR = __builtin_amdgcn_mfma_f32_32x32x16_bf16(WA1hi[0], b1h.v, aR, 0, 0, 0);
    aR = __builtin_amdgcn_mfma_f32_32x32x16_bf16(WA2hi[0], b2h.v, aR, 0, 0, 0);

    f32x16 aZ = __builtin_amdgcn_mfma_f32_32x32x16_bf16(GA1[1], bx1.v, zz16, 0, 0, 0);
    aZ = __builtin_amdgcn_mfma_f32_32x32x16_bf16(GA2[1], bx2.v, aZ, 0, 0, 0);
    aZ = __builtin_amdgcn_mfma_f32_32x32x16_bf16(WA1lo[1], b1h.v, aZ, 0, 0, 0);
    aZ = __builtin_amdgcn_mfma_f32_32x32x16_bf16(WA2lo[1], b2h.v, aZ, 0, 0, 0);
    aZ = __builtin_amdgcn_mfma_f32_32x32x16_bf16(WA1hi[1], b1l.v, aZ, 0, 0, 0);
    aZ = __builtin_amdgcn_mfma_f32_32x32x16_bf16(WA2hi[1], b2l.v, aZ, 0, 0, 0);
    aZ = __builtin_amdgcn_mfma_f32_32x32x16_bf16(WA1hi[1], b1h.v, aZ, 0, 0, 0);
    aZ = __builtin_amdgcn_mfma_f32_32x32x16_bf16(WA2hi[1], b2h.v, aZ, 0, 0, 0);

    f32x16 aNi = __builtin_amdgcn_mfma_f32_32x32x16_bf16(GA1[2], bx1.v, zz16, 0, 0, 0);
    aNi = __builtin_amdgcn_mfma_f32_32x32x16_bf16(GA2[2], bx2.v, aNi, 0, 0, 0);
    f32x16 aNh = __builtin_amdgcn_mfma_f32_32x32x16_bf16(WA1lo[2], b1h.v, bhnC, 0, 0, 0);
    aNh = __builtin_amdgcn_mfma_f32_32x32x16_bf16(WA2lo[2], b2h.v, aNh, 0, 0, 0);
    aNh = __builtin_amdgcn_mfma_f32_32x32x16_bf16(WA1hi[2], b1l.v, aNh, 0, 0, 0);
    aNh = __builtin_amdgcn_mfma_f32_32x32x16_bf16(WA2hi[2], b2l.v, aNh, 0, 0, 0);
    aNh = __builtin_amdgcn_mfma_f32_32x32x16_bf16(WA1hi[2], b1h.v, aNh, 0, 0, 0);
    aNh = __builtin_amdgcn_mfma_f32_32x32x16_bf16(WA2hi[2], b2h.v, aNh, 0, 0, 0);

    // ---- gates + h-update (16 units/lane, lane-local) ----
#pragma unroll
    for (int i = 0; i < 16; ++i) {
      float r = sigm(aR[i]);
      float z = sigm(aZ[i]);
      float n = tanh_fast(aNi[i] + r * aNh[i]);
      hst[i] = n + z * (hst[i] - n);
    }
  }

  // ---- epilogue: stage h (f32) through LDS, coalesced Y write ----
#pragma unroll
  for (int k = 0; k < 8; ++k) {
    int u = ((2 * k) & 3) + 8 * ((2 * k) >> 2) + 4 * s;
    *(float2*)(&Hfin[c * 36 + u]) = make_float2(hst[2 * k], hst[2 * k + 1]);
  }
  __syncthreads();
  {
    int mm = lane >> 1, half = lane & 1;
    int onode = blockIdx.x * 32 + mm;
    if (onode < N_NODES) {
      const float* src = &Hfin[mm * 36 + half * 16];
      float4 v0 = *(const float4*)(src);
      float4 v1 = *(const float4*)(src + 4);
      float4 v2 = *(const float4*)(src + 8);
      float4 v3 = *(const float4*)(src + 12);
      float* dst = Y + onode * CH + half * 16;
      *(float4*)(dst) = v0; *(float4*)(dst + 4) = v1;
      *(float4*)(dst + 8) = v2; *(float4*)(dst + 12) = v3;
    }
  }
}

// ---------------- degree counting ----------------
__global__ __launch_bounds__(256) void deg_kernel(
    const int* __restrict__ nodes, const int* __restrict__ edges,
    int* __restrict__ DN, int* __restrict__ DE)
{
  int i = blockIdx.x * 256 + threadIdx.x;
  if (i < N_INC) {
    atomicAdd(&DN[nodes[i]], 1);
    atomicAdd(&DE[edges[i]], 1);
  }
}

// ---------------- exclusive scan of edge degrees (single block, 2000) ----------------
__global__ __launch_bounds__(256) void scan_kernel(const int* __restrict__ DE, int* __restrict__ OFF)
{
  __shared__ int part[256];
  int t = threadIdx.x;
  int c[8]; int sum = 0;
#pragma unroll
  for (int u = 0; u < 8; ++u) {
    int idx = t * 8 + u;
    int x = (idx < N_EDGESC) ? DE[idx] : 0;
    c[u] = x; sum += x;
  }
  part[t] = sum;
  __syncthreads();
  for (int d = 1; d < 256; d <<= 1) {
    int v = (t >= d) ? part[t - d] : 0;
    __syncthreads();
    part[t] += v;
    __syncthreads();
  }
  int base = part[t] - sum;
#pragma unroll
  for (int u = 0; u < 8; ++u) {
    int idx = t * 8 + u;
    if (idx <= N_EDGESC) OFF[idx] = base;
    base += c[u];
  }
}

// ---------------- exclusive scan of node degrees (single block 1024, 50000) ----------------
#define NPER 49  // 1024*49 >= 50000
__global__ __launch_bounds__(1024) void nscan_kernel(
    const int* __restrict__ DN, int* __restrict__ NOFF, int* __restrict__ CUR)
{
  __shared__ int part[1024];
  int t = threadIdx.x;
  int cl[NPER]; int sum = 0;
  int base_i = t * NPER;
#pragma unroll
  for (int u = 0; u < NPER; ++u) {
    int idx = base_i + u;
    int x = (idx < N_NODES) ? DN[idx] : 0;
    cl[u] = x; sum += x;
  }
  part[t] = sum;
  __syncthreads();
  for (int d = 1; d < 1024; d <<= 1) {
    int v = (t >= d) ? part[t - d] : 0;
    __syncthreads();
    part[t] += v;
    __syncthreads();
  }
  int run = part[t] - sum;  // exclusive
#pragma unroll
  for (int u = 0; u < NPER; ++u) {
    int idx = base_i + u;
    if (idx < N_NODES) { NOFF[idx] = run; CUR[idx] = run; }
    run += cl[u];
  }
  if (t == 1023) NOFF[N_NODES] = run;
}

// ---------------- bucket incidences by node: INCN[pos] = edge ----------------
__global__ __launch_bounds__(256) void bucket_kernel(
    const int* __restrict__ nodes, const int* __restrict__ edges,
    int* __restrict__ CUR, int* __restrict__ INCN)
{
  int i = blockIdx.x * 256 + threadIdx.x;
  if (i < N_INC) {
    int p = atomicAdd(&CUR[nodes[i]], 1);
    INCN[p] = edges[i];
  }
}

// ---------------- node->edge gather-sum + fused theta (256 thr, 2-way ILP) ----------------
__global__ __launch_bounds__(256) void edge_gather_kernel(
    const float* __restrict__ X, const int* __restrict__ nodes,
    const int* __restrict__ OFF, const float* __restrict__ theta,
    float* __restrict__ EF)
{
  int e = blockIdx.x;
  int s = OFF[e], tE = OFF[e + 1];
  int f = threadIdx.x & 31, g = threadIdx.x >> 5;  // 8 row-groups
  float a0 = 0.f, a1 = 0.f;
  for (int i = s + g; i < tE; i += 16) {
    a0 += X[nodes[i] * CH + f];
    if (i + 8 < tE) a1 += X[nodes[i + 8] * CH + f];
  }
  __shared__ float red[8][33];
  __shared__ __align__(16) float e32[32];
  red[g][f] = a0 + a1;
  __syncthreads();
  if (threadIdx.x < 32) {
    float acc = 0.f;
#pragma unroll
    for (int r = 0; r < 8; ++r) acc += red[r][f];
    int cnt = tE - s;
    float binv = cnt > 0 ? 1.f / (float)cnt : 0.f;
    e32[f] = acc * binv;
    float s0 = 0.f, s1 = 0.f;
#pragma unroll
    for (int k4 = 0; k4 < 8; ++k4) {
      float4 ev = *(float4*)(e32 + 4 * k4);
      float4 tv = *(const float4*)(theta + f * CH + 4 * k4);
      s0 += tv.x * ev.x + tv.z * ev.z;
      s1 += tv.y * ev.y + tv.w * ev.w;
    }
    EF[e * CH + f] = s0 + s1;
  }
}

// ---------------- edge->node CSR gather + finalize (conv1) ----------------
__global__ __launch_bounds__(256) void node_gather_kernel(
    const float* __restrict__ EF, const int* __restrict__ NOFF,
    const int* __restrict__ INCN, const float* __restrict__ bias,
    float* __restrict__ X)
{
  int gid = blockIdx.x * 256 + threadIdx.x;
  if (gid >= N_NODES * 8) return;
  int n = gid >> 3, q = gid & 7;
  int s = NOFF[n], e = NOFF[n + 1];
  float4 acc = make_float4(0.f, 0.f, 0.f, 0.f);
  float4 acc2 = make_float4(0.f, 0.f, 0.f, 0.f);
  int k = s;
  for (; k + 1 < e; k += 2) {
    int e0 = INCN[k], e1 = INCN[k + 1];
    float4 v0 = *(const float4*)(EF + e0 * CH + q * 4);
    float4 v1 = *(const float4*)(EF + e1 * CH + q * 4);
    acc.x += v0.x; acc.y += v0.y; acc.z += v0.z; acc.w += v0.w;
    acc2.x += v1.x; acc2.y += v1.y; acc2.z += v1.z; acc2.w += v1.w;
  }
  if (k < e) {
    float4 v0 = *(const float4*)(EF + INCN[k] * CH + q * 4);
    acc.x += v0.x; acc.y += v0.y; acc.z += v0.z; acc.w += v0.w;
  }
  int d = e - s;
  float dinv = d > 0 ? 1.f / (float)d : 0.f;
  float4 b = *(const float4*)(bias + 4 * q);
  float4 o;
  o.x = leaky(fmaf(acc.x + acc2.x, dinv, b.x));
  o.y = leaky(fmaf(acc.y + acc2.y, dinv, b.y));
  o.z = leaky(fmaf(acc.z + acc2.z, dinv, b.z));
  o.w = leaky(fmaf(acc.w + acc2.w, dinv, b.w));
  *(float4*)(X + n * CH + 4 * q) = o;
}

// ---------------- edge->node CSR gather + finalize + output linear (conv2) ----------------
__global__ __launch_bounds__(256) void node_gather_out_kernel(
    const float* __restrict__ EF, const int* __restrict__ NOFF,
    const int* __restrict__ INCN, const float* __restrict__ bias,
    const float* __restrict__ w_out, const float* __restrict__ b_out,
    float* __restrict__ out)
{
  int gid = blockIdx.x * 256 + threadIdx.x;
  if (gid >= N_NODES * 8) return;
  int n = gid >> 3, q = gid & 7;
  int s = NOFF[n], e = NOFF[n + 1];
  float4 acc = make_float4(0.f, 0.f, 0.f, 0.f);
  float4 acc2 = make_float4(0.f, 0.f, 0.f, 0.f);
  int k = s;
  for (; k + 1 < e; k += 2) {
    int e0 = INCN[k], e1 = INCN[k + 1];
    float4 v0 = *(const float4*)(EF + e0 * CH + q * 4);
    float4 v1 = *(const float4*)(EF + e1 * CH + q * 4);
    acc.x += v0.x; acc.y += v0.y; acc.z += v0.z; acc.w += v0.w;
    acc2.x += v1.x; acc2.y += v1.y; acc2.z += v1.z; acc2.w += v1.w;
  }
  if (k < e) {
    float4 v0 = *(const float4*)(EF + INCN[k] * CH + q * 4);
    acc.x += v0.x; acc.y += v0.y; acc.z += v0.z; acc.w += v0.w;
  }
  int d = e - s;
  float dinv = d > 0 ? 1.f / (float)d : 0.f;
  float4 b = *(const float4*)(bias + 4 * q);
  float v0 = leaky(fmaf(acc.x + acc2.x, dinv, b.x));
  float v1 = leaky(fmaf(acc.y + acc2.y, dinv, b.y));
  float v2 = leaky(fmaf(acc.z + acc2.z, dinv, b.z));
  float v3 = leaky(fmaf(acc.w + acc2.w, dinv, b.w));

  float p[OUTF];
#pragma unroll
  for (int o = 0; o < OUTF; ++o) {
    const float* wr = w_out + o * CH + 4 * q;
    p[o] = v0 * wr[0] + v1 * wr[1] + v2 * wr[2] + v3 * wr[3];
  }
#pragma unroll
  for (int off = 1; off < 8; off <<= 1) {
#pragma unroll
    for (int o = 0; o < OUTF; ++o) p[o] += __shfl_xor(p[o], off);
  }
  if (q < OUTF) out[n * OUTF + q] = leaky(p[q] + b_out[q]);
}

extern "C" void kernel_launch(void* const* d_in, const int* in_sizes, int n_in,
                              void* d_out, int out_size, void* d_ws, size_t ws_size,
                              hipStream_t stream)
{
  const float* price   = (const float*)d_in[0];
  const int*   e_nodes = (const int*)d_in[1];
  const int*   e_edges = (const int*)d_in[2];
  const float* w_ih    = (const float*)d_in[6];
  const float* w_hh    = (const float*)d_in[7];
  const float* b_ih    = (const float*)d_in[8];
  const float* b_hh    = (const float*)d_in[9];
  const float* theta1  = (const float*)d_in[10];
  const float* bias1   = (const float*)d_in[11];
  const float* theta2  = (const float*)d_in[12];
  const float* bias2   = (const float*)d_in[13];
  const float* w_out   = (const float*)d_in[14];
  const float* b_out   = (const float*)d_in[15];
  float* out = (float*)d_out;

  float* ws   = (float*)d_ws;
  float* Y    = ws;                    // [50000*32]
  float* EF   = ws + 1600000;          // [2000*32]
  int*   DN   = (int*)(ws + 1664000);  // [50000]
  int*   DE   = DN + N_NODES;          // [2000]
  int*   OFF  = DE + N_EDGESC;         // [2001]
  int*   NOFF = OFF + N_EDGESC + 1;    // [50001]
  int*   CUR  = NOFF + N_NODES + 1;    // [50000]
  int*   INCN = CUR + N_NODES;         // [200000]

  hipMemsetAsync(DN, 0, (N_NODES + N_EDGESC) * sizeof(int), stream);
  deg_kernel<<<(N_INC + 255) / 256, 256, 0, stream>>>(e_nodes, e_edges, DN, DE);
  scan_kernel<<<1, 256, 0, stream>>>(DE, OFF);
  nscan_kernel<<<1, 1024, 0, stream>>>(DN, NOFF, CUR);
  bucket_kernel<<<(N_INC + 255) / 256, 256, 0, stream>>>(e_nodes, e_edges, CUR, INCN);

  // 1 wave = 32 nodes (one 32x32 tile) -> 1563 blocks
  gru_mfma_kernel<<<(N_NODES + 31) / 32, 64, 0, stream>>>(
      price, w_ih, w_hh, b_ih, b_hh, Y);

  // conv1: node->edge (+theta1), edge->node CSR gather (+bias1+leaky)
  edge_gather_kernel<<<N_EDGESC, 256, 0, stream>>>(Y, e_nodes, OFF, theta1, EF);
  node_gather_kernel<<<(N_NODES * 8 + 255) / 256, 256, 0, stream>>>(EF, NOFF, INCN, bias1, Y);

  // conv2: node->edge (+theta2), edge->node CSR gather (+bias2+leaky+w_out+b_out)
  edge_gather_kernel<<<N_EDGESC, 256, 0, stream>>>(Y, e_nodes, OFF, theta2, EF);
  node_gather_out_kernel<<<(N_NODES * 8 + 255) / 256, 256, 0, stream>>>(
      EF, NOFF, INCN, bias2, w_out, b_out, out);
}